// Round 1
// baseline (214.504 us; speedup 1.0000x reference)
//
#include <hip/hip_runtime.h>
#include <cstddef>

// MPS classifier: SIZE=784, D=32, DLOC=2, NUM_LABELS=10, LABEL_SITE=392, B=128
// Strategy: 256 chains (128 batch x 2 halves), each split into 16 segments.
// All matrices stored "transposed" (stored[a*32+b] = P[b][a]) so the matmul
// primitive reads both operands as contiguous float4s from LDS.
//
// ws layout: 4096 segment slots x 1024 floats = 16.78 MB.
// K2 writes quarter products in-place into slot 4q.

__device__ __forceinline__ void copy1024_l(float* __restrict__ dst,
                                           const float* __restrict__ src, int lane) {
  const float4* s = (const float4*)src;
  float4* d = (float4*)dst;
#pragma unroll
  for (int u = 0; u < 4; ++u) d[lane + 64 * u] = s[lane + 64 * u];
}

// srcT stores S transposed (srcT[r*32+c] = S[c][r]); produce Br[j*32+k] = S[j][k].
__device__ __forceinline__ void stage_T(const float* __restrict__ srcT,
                                        float* __restrict__ Br, int lane) {
#pragma unroll
  for (int u = 0; u < 4; ++u) {
    int p = lane + 64 * u;
    int r = p >> 3;
    int c0 = (p & 7) << 2;
    float4 f = *(const float4*)&srcT[r * 32 + c0];
    Br[(c0 + 0) * 32 + r] = f.x;
    Br[(c0 + 1) * 32 + r] = f.y;
    Br[(c0 + 2) * 32 + r] = f.z;
    Br[(c0 + 3) * 32 + r] = f.w;
  }
}

// P = X * Y.  A[j*32+i] = X[i][j] (X transposed), Br[j*32+k] = Y[j][k].
// Writes An[k*32+i] = P[i][k]  (i.e. P transposed -> usable as next A).
__device__ __forceinline__ void mm_step(const float* __restrict__ A,
                                        const float* __restrict__ Br,
                                        float* __restrict__ An, int lane) {
  const int i0 = (lane >> 3) << 2;
  const int k0 = (lane & 7) << 2;
  float acc[4][4];
#pragma unroll
  for (int r = 0; r < 4; ++r)
#pragma unroll
    for (int c = 0; c < 4; ++c) acc[r][c] = 0.0f;
#pragma unroll
  for (int j = 0; j < 32; ++j) {
    float4 av = *(const float4*)&A[j * 32 + i0];
    float4 bv = *(const float4*)&Br[j * 32 + k0];
    float af[4] = {av.x, av.y, av.z, av.w};
    float bf[4] = {bv.x, bv.y, bv.z, bv.w};
#pragma unroll
    for (int r = 0; r < 4; ++r)
#pragma unroll
      for (int c = 0; c < 4; ++c) acc[r][c] += af[r] * bf[c];
  }
#pragma unroll
  for (int c = 0; c < 4; ++c) {
    float4 w = make_float4(acc[0][c], acc[1][c], acc[2][c], acc[3][c]);
    *(float4*)&An[(k0 + c) * 32 + i0] = w;
  }
}

// K1: one wave per (chain, segment). 4096 blocks x 64 threads.
__global__ __launch_bounds__(64) void seg_kernel(const float* __restrict__ x,
                                                 const float* __restrict__ core,
                                                 float* __restrict__ segout) {
  __shared__ float lds[3072];
  const int lane = threadIdx.x;
  const int task = blockIdx.x;      // 0..4095
  const int chain = task >> 4;      // 0..255 = b*2 + h
  const int t = task & 15;
  const int b = chain >> 1;
  const int h = chain & 1;
  const int start = (t < 8) ? 25 * t : 200 + 24 * (t - 8);
  const int len = (t < 8) ? 25 : 24;  // 8*25 + 8*24 = 392
  const int sbase = h * 392 + start;

  float* A = lds;
  float* An = lds + 1024;
  float* Br = lds + 2048;

  // A = Identity (transposed identity == identity)
#pragma unroll
  for (int u = 0; u < 16; ++u) {
    int e = lane + 64 * u;
    A[e] = ((e >> 5) == (e & 31)) ? 1.0f : 0.0f;
  }

  for (int step = 0; step < len; ++step) {
    const int s = sbase + step;
    const float xv = x[b * 784 + s];
    const float4* cv = (const float4*)(core + (size_t)s * 2048);
    // stage blended M: core layout [i][j][d], d interleaved -> one float4 = 2 elems
#pragma unroll
    for (int u = 0; u < 8; ++u) {
      int p = lane + 64 * u;           // pair index 0..511, elements 2p, 2p+1
      float4 f = cv[p];
      float2 w;
      w.x = f.x + xv * (f.y - f.x);
      w.y = f.z + xv * (f.w - f.z);
      *(float2*)&Br[2 * p] = w;
    }
    __syncthreads();
    mm_step(A, Br, An, lane);
    __syncthreads();
    float* tmp = A; A = An; An = tmp;
  }

  // write segment product (transposed form) to its slot
  float4* o = (float4*)(segout + (size_t)task * 1024);
  const float4* a4 = (const float4*)A;
#pragma unroll
  for (int u = 0; u < 4; ++u) o[lane + 64 * u] = a4[lane + 64 * u];
}

// K2: combine 4 consecutive segments -> quarter product, in-place at slot 4q.
// 1024 blocks x 64 threads.
__global__ __launch_bounds__(64) void comb_kernel(float* __restrict__ ws) {
  __shared__ float lds[3072];
  const int lane = threadIdx.x;
  const int q = blockIdx.x;  // 0..1023 ; segment tasks 4q..4q+3
  float* R0 = lds;
  float* R1 = lds + 1024;
  float* R2 = lds + 2048;

  copy1024_l(R0, ws + (size_t)1024 * (4 * q), lane);
  float* A = R0;
  float* An = R1;
  for (int m = 1; m < 4; ++m) {
    stage_T(ws + (size_t)1024 * (4 * q + m), R2, lane);
    __syncthreads();
    mm_step(A, R2, An, lane);
    __syncthreads();
    float* tmp = A; A = An; An = tmp;
  }
  // A == R1 holds (S0*S1*S2*S3)^T ; write back to slot 4q
  float4* o = (float4*)(ws + (size_t)1024 * (4 * q));
  const float4* a4 = (const float4*)A;
#pragma unroll
  for (int u = 0; u < 4; ++u) o[lane + 64 * u] = a4[lane + 64 * u];
}

// K3: per batch: combine quarters of both halves, F = R*L, contract with label.
// 128 blocks x 64 threads.
__global__ __launch_bounds__(64) void final_kernel(const float* __restrict__ ws,
                                                   const float* __restrict__ label,
                                                   float* __restrict__ out) {
  __shared__ float lds[4096];
  const int lane = threadIdx.x;
  const int b = blockIdx.x;
  float* R0 = lds;
  float* R1 = lds + 1024;
  float* R2 = lds + 2048;
  float* R3 = lds + 3072;

  // ---- left chain (2b): quarters at slots 4*(chain*4+g) ----
  {
    const int chain = 2 * b;
    copy1024_l(R0, ws + (size_t)4096 * (chain * 4), lane);
    float* A = R0;
    float* An = R1;
    for (int m = 1; m < 4; ++m) {
      stage_T(ws + (size_t)4096 * (chain * 4 + m), R2, lane);
      __syncthreads();
      mm_step(A, R2, An, lane);
      __syncthreads();
      float* tmp = A; A = An; An = tmp;
    }
    // A == R1 = Left^T ; save to R3
    copy1024_l(R3, A, lane);
    __syncthreads();
  }
  // ---- right chain (2b+1) ----
  float* RT;
  {
    const int chain = 2 * b + 1;
    copy1024_l(R0, ws + (size_t)4096 * (chain * 4), lane);
    float* A = R0;
    float* An = R1;
    for (int m = 1; m < 4; ++m) {
      stage_T(ws + (size_t)4096 * (chain * 4 + m), R2, lane);
      __syncthreads();
      mm_step(A, R2, An, lane);
      __syncthreads();
      float* tmp = A; A = An; An = tmp;
    }
    RT = A;  // == R1 = Right^T
  }
  // ---- F = Right * Left : A-form needs Right^T (have), B-form needs Left (stage-T from R3) ----
  stage_T(R3, R2, lane);
  __syncthreads();
  mm_step(RT, R2, R0, lane);  // R0[c*32+r] = F[r][c] => F[k][j] at R0[j*32+k]
  __syncthreads();

  // score[l] = sum_{j,k} F[k,j]*label[j,k,l] = sum_e R0[e]*label[e*10+l]
  float part[10];
#pragma unroll
  for (int l = 0; l < 10; ++l) part[l] = 0.0f;
  for (int u = 0; u < 16; ++u) {
    int e = lane + 64 * u;
    float v = R0[e];
    const float* lb = label + (size_t)e * 10;
#pragma unroll
    for (int l = 0; l < 10; ++l) part[l] += v * lb[l];
  }
#pragma unroll
  for (int l = 0; l < 10; ++l) {
#pragma unroll
    for (int off = 32; off > 0; off >>= 1) part[l] += __shfl_xor(part[l], off, 64);
  }
  if (lane == 0) {
#pragma unroll
    for (int l = 0; l < 10; ++l) out[b * 10 + l] = part[l];
  }
}

extern "C" void kernel_launch(void* const* d_in, const int* in_sizes, int n_in,
                              void* d_out, int out_size, void* d_ws, size_t ws_size,
                              hipStream_t stream) {
  const float* x = (const float*)d_in[0];      // (128, 784)
  const float* core = (const float*)d_in[1];   // (784, 32, 32, 2)
  const float* label = (const float*)d_in[2];  // (32, 32, 10)
  float* out = (float*)d_out;                  // (128, 10)
  float* ws = (float*)d_ws;                    // needs 4096*1024*4 = 16.78 MB

  hipLaunchKernelGGL(seg_kernel, dim3(4096), dim3(64), 0, stream, x, core, ws);
  hipLaunchKernelGGL(comb_kernel, dim3(1024), dim3(64), 0, stream, ws);
  hipLaunchKernelGGL(final_kernel, dim3(128), dim3(64), 0, stream, ws, label, out);
}

// Round 3
// 167.511 us; speedup vs baseline: 1.2805x; 1.2805x over previous
//
#include <hip/hip_runtime.h>
#include <cstddef>

// MPS classifier: SIZE=784, D=32, DLOC=2, NUM_LABELS=10, LABEL_SITE=392, B=128
//
// K1 (seg_mfma): one wave per (chain, segment). Running 32x32 product lives in
//   MFMA accumulators; per site computes acc += E_s * bf16(acc) via 8
//   v_mfma_f32_16x16x16_bf16 (C/D layout == B layout for K=16, so the product
//   feeds back with only an in-register fp32->bf16 pack). A operand (E_s)
//   comes straight from global; NO LDS in the loop.
// K2 (chain_mfma): one wave per chain, folds its 16 segment products with a
//   3-term bf16 hi/lo split (S_t not near identity).
// K3 (final_k): per batch, F = Right*Left (VALU mm_step, proven round 1),
//   contract with label.

typedef short bfrag __attribute__((ext_vector_type(4)));   // 4 bf16
typedef float facc  __attribute__((ext_vector_type(4)));   // 4 fp32

// NOTE: guard must let the HOST pass parse this file — host clang has no
// amdgcn builtins, so the #error is device-pass-only (round-2 failure mode).
#if !defined(__HIP_DEVICE_COMPILE__)
#define MFMA16(a, b, c) (c)  // host stub, never executed
#elif __has_builtin(__builtin_amdgcn_mfma_f32_16x16x16bf16_1k)
#define MFMA16(a, b, c) __builtin_amdgcn_mfma_f32_16x16x16bf16_1k(a, b, c, 0, 0, 0)
#elif __has_builtin(__builtin_amdgcn_mfma_f32_16x16x16_bf16)
#define MFMA16(a, b, c) __builtin_amdgcn_mfma_f32_16x16x16_bf16(a, b, c, 0, 0, 0)
#else
#error "no 16x16x16 bf16 MFMA builtin on this target"
#endif

__device__ __forceinline__ short bf16h(float v) {
  unsigned u = __float_as_uint(v) + 0x8000u;  // round-half-up to bf16
  return (short)(u >> 16);
}

__device__ __forceinline__ bfrag pack4(const facc v) {
  bfrag r;
#pragma unroll
  for (int j = 0; j < 4; ++j) r[j] = bf16h(v[j]);
  return r;
}

// fp32 -> (hi bf16 rounded, lo bf16 of remainder)
__device__ __forceinline__ void split4(const float* v, bfrag& hi, bfrag& lo) {
#pragma unroll
  for (int j = 0; j < 4; ++j) {
    unsigned u = (__float_as_uint(v[j]) + 0x8000u) & 0xFFFF0000u;
    hi[j] = (short)(u >> 16);
    float lf = v[j] - __uint_as_float(u);
    lo[j] = bf16h(lf);
  }
}

// ---------------------------------------------------------------------------
// K1: 1024 blocks x 256 threads. Block = (h,t) combo x 4 batches (one/wave).
// ---------------------------------------------------------------------------
__global__ __launch_bounds__(256) void seg_mfma(const float* __restrict__ x,
                                                const float* __restrict__ core,
                                                float* __restrict__ ws) {
  const int lane = threadIdx.x & 63;
  const int w = threadIdx.x >> 6;
  const int col16 = lane & 15;
  const int q = lane >> 4;

  const int bid = blockIdx.x;     // 0..1023
  const int combo = bid >> 5;     // 0..31 = h*16 + t
  const int g = bid & 31;         // batch group
  const int h = combo >> 4;
  const int t = combo & 15;
  const int b = g * 4 + w;

  const int start = (t < 8) ? 25 * t : 200 + 24 * (t - 8);
  const int len = (t < 8) ? 25 : 24;
  const int s_lo = h * 392 + start;
  const int s_hi = s_lo + len - 1;

  // diag subtraction pattern: frag element j is column 4q+j; diagonal iff ==col16
  float ds[4];
#pragma unroll
  for (int j = 0; j < 4; ++j) ds[j] = (4 * q + j == col16) ? 1.0f : 0.0f;

  // acc[r][c] holds P[16r + 4q + reg][16c + col16]; init P = I
  facc acc[2][2];
#pragma unroll
  for (int r = 0; r < 2; ++r)
#pragma unroll
    for (int c = 0; c < 2; ++c)
#pragma unroll
      for (int j = 0; j < 4; ++j)
        acc[r][c][j] = (16 * r + 4 * q + j == 16 * c + col16) ? 1.0f : 0.0f;

  // per-lane float4 offsets within a site block (512 float4s/site)
  // element (i, c0 pair p): f4idx = i*16 + 8*h2 + 2*q + p, i = 16r+col16
  int off[2][2][2];
#pragma unroll
  for (int r = 0; r < 2; ++r)
#pragma unroll
    for (int h2 = 0; h2 < 2; ++h2)
#pragma unroll
      for (int p = 0; p < 2; ++p)
        off[r][h2][p] = (16 * r + col16) * 16 + 8 * h2 + 2 * q + p;

  const float4* cp = (const float4*)core;
  const float* xb = x + b * 784;

  for (int s = s_hi; s >= s_lo; --s) {
    __builtin_amdgcn_s_barrier();  // keep the 4 waves on the same site (L1 reuse)
    const size_t sbase = (size_t)s * 512;
    const float xv = xb[s];

    float4 raw[2][2][2];
#pragma unroll
    for (int r = 0; r < 2; ++r)
#pragma unroll
      for (int h2 = 0; h2 < 2; ++h2)
#pragma unroll
        for (int p = 0; p < 2; ++p)
          raw[r][h2][p] = cp[sbase + off[r][h2][p]];

    // snapshot B = bf16(P_old) BEFORE any accumulation
    bfrag B[2][2];
#pragma unroll
    for (int h2 = 0; h2 < 2; ++h2)
#pragma unroll
      for (int c = 0; c < 2; ++c) B[h2][c] = pack4(acc[h2][c]);

    // A = E_s fragments: A[r][h2][j] = E[16r+col16][16h2+4q+j]
    bfrag A[2][2];
#pragma unroll
    for (int r = 0; r < 2; ++r)
#pragma unroll
      for (int h2 = 0; h2 < 2; ++h2) {
        float4 f0 = raw[r][h2][0];
        float4 f1 = raw[r][h2][1];
        float e0 = f0.x + xv * (f0.y - f0.x);
        float e1 = f0.z + xv * (f0.w - f0.z);
        float e2 = f1.x + xv * (f1.y - f1.x);
        float e3 = f1.z + xv * (f1.w - f1.z);
        if (r == h2) { e0 -= ds[0]; e1 -= ds[1]; e2 -= ds[2]; e3 -= ds[3]; }
        bfrag a; a[0] = bf16h(e0); a[1] = bf16h(e1); a[2] = bf16h(e2); a[3] = bf16h(e3);
        A[r][h2] = a;
      }

    // acc += E * P_old  (8 MFMAs)
#pragma unroll
    for (int r = 0; r < 2; ++r)
#pragma unroll
      for (int c = 0; c < 2; ++c) {
        acc[r][c] = MFMA16(A[r][0], B[0][c], acc[r][c]);
        acc[r][c] = MFMA16(A[r][1], B[1][c], acc[r][c]);
      }
  }

  // store S_t col-major: ws[slot][col*32 + row] = P[row][col]
  const size_t slot = (size_t)((b * 2 + h) * 16 + t) * 1024;
#pragma unroll
  for (int r = 0; r < 2; ++r)
#pragma unroll
    for (int c = 0; c < 2; ++c) {
      facc v = acc[r][c];
      *(float4*)&ws[slot + (size_t)(16 * c + col16) * 32 + 16 * r + 4 * q] =
          make_float4(v[0], v[1], v[2], v[3]);
    }
}

// ---------------------------------------------------------------------------
// K2: 256 blocks x 64 threads. Fold 16 segment products of one chain.
// ---------------------------------------------------------------------------
__global__ __launch_bounds__(64) void chain_mfma(float* __restrict__ ws) {
  const int lane = threadIdx.x;
  const int col16 = lane & 15;
  const int q = lane >> 4;
  const int chain = blockIdx.x;  // 0..255

  facc acc[2][2];
#pragma unroll
  for (int r = 0; r < 2; ++r)
#pragma unroll
    for (int c = 0; c < 2; ++c)
#pragma unroll
      for (int j = 0; j < 4; ++j)
        acc[r][c][j] = (16 * r + 4 * q + j == 16 * c + col16) ? 1.0f : 0.0f;

  for (int t = 15; t >= 0; --t) {
    const float* sp = ws + (size_t)(chain * 16 + t) * 1024;

    // A[r][h2][j] = S_t[16r+col16][16h2+4q+j] = sp[(16h2+4q+j)*32 + 16r+col16]
    float av[2][2][4];
#pragma unroll
    for (int r = 0; r < 2; ++r)
#pragma unroll
      for (int h2 = 0; h2 < 2; ++h2)
#pragma unroll
        for (int j = 0; j < 4; ++j)
          av[r][h2][j] = sp[(size_t)(16 * h2 + 4 * q + j) * 32 + 16 * r + col16];

    bfrag Ahi[2][2], Alo[2][2], Bhi[2][2], Blo[2][2];
#pragma unroll
    for (int r = 0; r < 2; ++r)
#pragma unroll
      for (int h2 = 0; h2 < 2; ++h2) split4(av[r][h2], Ahi[r][h2], Alo[r][h2]);
#pragma unroll
    for (int h2 = 0; h2 < 2; ++h2)
#pragma unroll
      for (int c = 0; c < 2; ++c) {
        float bv[4] = {acc[h2][c][0], acc[h2][c][1], acc[h2][c][2], acc[h2][c][3]};
        split4(bv, Bhi[h2][c], Blo[h2][c]);
      }

    // P_new = S_t * P_old (fresh accumulator, 3-term split)
    facc nacc[2][2];
#pragma unroll
    for (int r = 0; r < 2; ++r)
#pragma unroll
      for (int c = 0; c < 2; ++c) {
        facc z;
#pragma unroll
        for (int j = 0; j < 4; ++j) z[j] = 0.0f;
#pragma unroll
        for (int h2 = 0; h2 < 2; ++h2) {
          z = MFMA16(Ahi[r][h2], Bhi[h2][c], z);
          z = MFMA16(Ahi[r][h2], Blo[h2][c], z);
          z = MFMA16(Alo[r][h2], Bhi[h2][c], z);
        }
        nacc[r][c] = z;
      }
#pragma unroll
    for (int r = 0; r < 2; ++r)
#pragma unroll
      for (int c = 0; c < 2; ++c) acc[r][c] = nacc[r][c];
  }

  // write chain product col-major into slot chain*16
  const size_t slot = (size_t)(chain * 16) * 1024;
#pragma unroll
  for (int r = 0; r < 2; ++r)
#pragma unroll
    for (int c = 0; c < 2; ++c) {
      facc v = acc[r][c];
      *(float4*)&ws[slot + (size_t)(16 * c + col16) * 32 + 16 * r + 4 * q] =
          make_float4(v[0], v[1], v[2], v[3]);
    }
}

// ---------------------------------------------------------------------------
// K3 helpers (VALU path, verified round 1)
// ---------------------------------------------------------------------------
// srcT stores S transposed (srcT[r*32+c] = S[c][r]); produce Br[j*32+k] = S[j][k].
__device__ __forceinline__ void stage_T(const float* __restrict__ srcT,
                                        float* __restrict__ Br, int lane) {
#pragma unroll
  for (int u = 0; u < 4; ++u) {
    int p = lane + 64 * u;
    int r = p >> 3;
    int c0 = (p & 7) << 2;
    float4 f = *(const float4*)&srcT[r * 32 + c0];
    Br[(c0 + 0) * 32 + r] = f.x;
    Br[(c0 + 1) * 32 + r] = f.y;
    Br[(c0 + 2) * 32 + r] = f.z;
    Br[(c0 + 3) * 32 + r] = f.w;
  }
}

// P = X * Y.  A[j*32+i] = X[i][j], Br[j*32+k] = Y[j][k]. Writes An[k*32+i] = P[i][k].
__device__ __forceinline__ void mm_step(const float* __restrict__ A,
                                        const float* __restrict__ Br,
                                        float* __restrict__ An, int lane) {
  const int i0 = (lane >> 3) << 2;
  const int k0 = (lane & 7) << 2;
  float acc[4][4];
#pragma unroll
  for (int r = 0; r < 4; ++r)
#pragma unroll
    for (int c = 0; c < 4; ++c) acc[r][c] = 0.0f;
#pragma unroll
  for (int j = 0; j < 32; ++j) {
    float4 av = *(const float4*)&A[j * 32 + i0];
    float4 bv = *(const float4*)&Br[j * 32 + k0];
    float af[4] = {av.x, av.y, av.z, av.w};
    float bf[4] = {bv.x, bv.y, bv.z, bv.w};
#pragma unroll
    for (int r = 0; r < 4; ++r)
#pragma unroll
      for (int c = 0; c < 4; ++c) acc[r][c] += af[r] * bf[c];
  }
#pragma unroll
  for (int c = 0; c < 4; ++c) {
    float4 wv = make_float4(acc[0][c], acc[1][c], acc[2][c], acc[3][c]);
    *(float4*)&An[(k0 + c) * 32 + i0] = wv;
  }
}

// K3: 128 blocks x 64 threads. F = Right*Left, contract with label.
__global__ __launch_bounds__(64) void final_k(const float* __restrict__ ws,
                                              const float* __restrict__ label,
                                              float* __restrict__ out) {
  __shared__ float lds[2048];
  const int lane = threadIdx.x;
  const int b = blockIdx.x;
  float* Br = lds;
  float* R0 = lds + 1024;

  const float* Lt = ws + (size_t)((2 * b) * 16) * 1024;      // stored[a*32+e]=L[e][a]
  const float* Rt = ws + (size_t)((2 * b + 1) * 16) * 1024;  // A-form of Right

  stage_T(Lt, Br, lane);  // Br[j*32+k] = L[j][k]
  __syncthreads();
  mm_step(Rt, Br, R0, lane);  // R0[j*32+k] = F[k][j], F = R*L
  __syncthreads();

  // score[l] = sum_e R0[e] * label[e*10+l]
  float part[10];
#pragma unroll
  for (int l = 0; l < 10; ++l) part[l] = 0.0f;
  for (int u = 0; u < 16; ++u) {
    int e = lane + 64 * u;
    float v = R0[e];
    const float* lb = label + (size_t)e * 10;
#pragma unroll
    for (int l = 0; l < 10; ++l) part[l] += v * lb[l];
  }
#pragma unroll
  for (int l = 0; l < 10; ++l) {
#pragma unroll
    for (int off = 32; off > 0; off >>= 1) part[l] += __shfl_xor(part[l], off, 64);
  }
  if (lane == 0) {
#pragma unroll
    for (int l = 0; l < 10; ++l) out[b * 10 + l] = part[l];
  }
}

extern "C" void kernel_launch(void* const* d_in, const int* in_sizes, int n_in,
                              void* d_out, int out_size, void* d_ws, size_t ws_size,
                              hipStream_t stream) {
  const float* x = (const float*)d_in[0];      // (128, 784)
  const float* core = (const float*)d_in[1];   // (784, 32, 32, 2)
  const float* label = (const float*)d_in[2];  // (32, 32, 10)
  float* out = (float*)d_out;                  // (128, 10)
  float* ws = (float*)d_ws;                    // 4096 slots x 1024 f = 16.78 MB

  hipLaunchKernelGGL(seg_mfma, dim3(1024), dim3(256), 0, stream, x, core, ws);
  hipLaunchKernelGGL(chain_mfma, dim3(256), dim3(64), 0, stream, ws);
  hipLaunchKernelGGL(final_k, dim3(128), dim3(64), 0, stream, ws, label, out);
}

// Round 4
// 164.990 us; speedup vs baseline: 1.3001x; 1.0153x over previous
//
#include <hip/hip_runtime.h>
#include <cstddef>

// MPS classifier: SIZE=784, D=32, DLOC=2, NUM_LABELS=10, LABEL_SITE=392, B=128
//
// Round-4 changes vs round 3 (97us K1 was latency-serialized: VALUBusy 22%,
// MfmaUtil 5%, 73% idle-issue):
//  - K1: register double-buffer prefetch of next site's 8 float4 loads; no
//    per-site barrier. Segment product stored ROW-major (scalar stores) so the
//    fold kernel loads contiguous float4 fragments.
//  - K2+K3 fused into finish_k (128 blocks x 2 waves): each wave folds one
//    chain (prefetched), LDS exchange, mm_step + label contraction.

typedef short bfrag __attribute__((ext_vector_type(4)));   // 4 bf16
typedef float facc  __attribute__((ext_vector_type(4)));   // 4 fp32

#if !defined(__HIP_DEVICE_COMPILE__)
#define MFMA16(a, b, c) (c)  // host-pass stub (host clang lacks amdgcn builtins)
#elif __has_builtin(__builtin_amdgcn_mfma_f32_16x16x16bf16_1k)
#define MFMA16(a, b, c) __builtin_amdgcn_mfma_f32_16x16x16bf16_1k(a, b, c, 0, 0, 0)
#elif __has_builtin(__builtin_amdgcn_mfma_f32_16x16x16_bf16)
#define MFMA16(a, b, c) __builtin_amdgcn_mfma_f32_16x16x16_bf16(a, b, c, 0, 0, 0)
#else
#error "no 16x16x16 bf16 MFMA builtin on this target"
#endif

__device__ __forceinline__ short bf16h(float v) {
  unsigned u = __float_as_uint(v) + 0x8000u;  // round-half-up to bf16
  return (short)(u >> 16);
}

__device__ __forceinline__ bfrag pack4(const facc v) {
  bfrag r;
#pragma unroll
  for (int j = 0; j < 4; ++j) r[j] = bf16h(v[j]);
  return r;
}

// fp32 -> (hi bf16 rounded, lo bf16 of remainder)
__device__ __forceinline__ void split4(const float* v, bfrag& hi, bfrag& lo) {
#pragma unroll
  for (int j = 0; j < 4; ++j) {
    unsigned u = (__float_as_uint(v[j]) + 0x8000u) & 0xFFFF0000u;
    hi[j] = (short)(u >> 16);
    float lf = v[j] - __uint_as_float(u);
    lo[j] = bf16h(lf);
  }
}

// One site update: acc += E_s * bf16(acc).  acc[r][c][j] = P[16r+4q+j][16c+col16].
__device__ __forceinline__ void site_update(facc (&acc)[2][2],
                                            const float4 (&raw)[2][2][2],
                                            float xv, const float (&ds)[4]) {
  // snapshot B = bf16(P_old) BEFORE any accumulation (C/D layout == B layout, K=16)
  bfrag B[2][2];
#pragma unroll
  for (int h2 = 0; h2 < 2; ++h2)
#pragma unroll
    for (int c = 0; c < 2; ++c) B[h2][c] = pack4(acc[h2][c]);

  bfrag A[2][2];
#pragma unroll
  for (int r = 0; r < 2; ++r)
#pragma unroll
    for (int h2 = 0; h2 < 2; ++h2) {
      float4 f0 = raw[r][h2][0];
      float4 f1 = raw[r][h2][1];
      float e0 = f0.x + xv * (f0.y - f0.x);
      float e1 = f0.z + xv * (f0.w - f0.z);
      float e2 = f1.x + xv * (f1.y - f1.x);
      float e3 = f1.z + xv * (f1.w - f1.z);
      if (r == h2) { e0 -= ds[0]; e1 -= ds[1]; e2 -= ds[2]; e3 -= ds[3]; }
      bfrag a; a[0] = bf16h(e0); a[1] = bf16h(e1); a[2] = bf16h(e2); a[3] = bf16h(e3);
      A[r][h2] = a;
    }

#pragma unroll
  for (int r = 0; r < 2; ++r)
#pragma unroll
    for (int c = 0; c < 2; ++c) {
      acc[r][c] = MFMA16(A[r][0], B[0][c], acc[r][c]);
      acc[r][c] = MFMA16(A[r][1], B[1][c], acc[r][c]);
    }
}

// ---------------------------------------------------------------------------
// K1: 1024 blocks x 256 threads. Block = (h,t) combo x 4 batches (one/wave).
// Register double-buffered site loads; no per-site barrier.
// ---------------------------------------------------------------------------
__global__ __launch_bounds__(256, 4) void seg_mfma(const float* __restrict__ x,
                                                   const float* __restrict__ core,
                                                   float* __restrict__ ws) {
  const int lane = threadIdx.x & 63;
  const int w = threadIdx.x >> 6;
  const int col16 = lane & 15;
  const int q = lane >> 4;

  const int bid = blockIdx.x;     // 0..1023
  const int combo = bid >> 5;     // 0..31 = h*16 + t
  const int g = bid & 31;         // batch group
  const int h = combo >> 4;
  const int t = combo & 15;
  const int b = g * 4 + w;

  const int start = (t < 8) ? 25 * t : 200 + 24 * (t - 8);
  const int len = (t < 8) ? 25 : 24;
  const int s_lo = h * 392 + start;
  const int s_hi = s_lo + len - 1;

  float ds[4];
#pragma unroll
  for (int j = 0; j < 4; ++j) ds[j] = (4 * q + j == col16) ? 1.0f : 0.0f;

  facc acc[2][2];
#pragma unroll
  for (int r = 0; r < 2; ++r)
#pragma unroll
    for (int c = 0; c < 2; ++c)
#pragma unroll
      for (int j = 0; j < 4; ++j)
        acc[r][c][j] = (16 * r + 4 * q + j == 16 * c + col16) ? 1.0f : 0.0f;

  // per-lane float4 offsets within a site block (512 float4s/site)
  int off[2][2][2];
#pragma unroll
  for (int r = 0; r < 2; ++r)
#pragma unroll
    for (int h2 = 0; h2 < 2; ++h2)
#pragma unroll
      for (int p = 0; p < 2; ++p)
        off[r][h2][p] = (16 * r + col16) * 16 + 8 * h2 + 2 * q + p;

  const float4* cp = (const float4*)core;
  const float* xb = x + b * 784;

  // preload first site
  float4 raw[2][2][2];
  float xv;
  {
    const size_t sb = (size_t)s_hi * 512;
#pragma unroll
    for (int r = 0; r < 2; ++r)
#pragma unroll
      for (int h2 = 0; h2 < 2; ++h2)
#pragma unroll
        for (int p = 0; p < 2; ++p) raw[r][h2][p] = cp[sb + off[r][h2][p]];
    xv = xb[s_hi];
  }

  for (int s = s_hi; s > s_lo; --s) {
    // prefetch site s-1 (issued before the dependent compute of site s)
    float4 nraw[2][2][2];
    const size_t nb = (size_t)(s - 1) * 512;
#pragma unroll
    for (int r = 0; r < 2; ++r)
#pragma unroll
      for (int h2 = 0; h2 < 2; ++h2)
#pragma unroll
        for (int p = 0; p < 2; ++p) nraw[r][h2][p] = cp[nb + off[r][h2][p]];
    float nxv = xb[s - 1];

    site_update(acc, raw, xv, ds);

#pragma unroll
    for (int r = 0; r < 2; ++r)
#pragma unroll
      for (int h2 = 0; h2 < 2; ++h2)
#pragma unroll
        for (int p = 0; p < 2; ++p) raw[r][h2][p] = nraw[r][h2][p];
    xv = nxv;
  }
  site_update(acc, raw, xv, ds);  // s_lo

  // store segment product ROW-major: ws[slot + row*32 + col] = P[row][col]
  const size_t slot = (size_t)((b * 2 + h) * 16 + t) * 1024;
#pragma unroll
  for (int r = 0; r < 2; ++r)
#pragma unroll
    for (int c = 0; c < 2; ++c)
#pragma unroll
      for (int j = 0; j < 4; ++j)
        ws[slot + (size_t)(16 * r + 4 * q + j) * 32 + 16 * c + col16] = acc[r][c][j];
}

// One fold step: acc = S_t * acc (3-term bf16 hi/lo split).
// av[r][h2] = float4 of S_t[16r+col16][16h2+4q .. +3] (row-major source).
__device__ __forceinline__ void fold_step(facc (&acc)[2][2], const float4 (&av)[2][2],
                                          int /*unused*/) {
  bfrag Ahi[2][2], Alo[2][2], Bhi[2][2], Blo[2][2];
#pragma unroll
  for (int r = 0; r < 2; ++r)
#pragma unroll
    for (int h2 = 0; h2 < 2; ++h2) {
      float v[4] = {av[r][h2].x, av[r][h2].y, av[r][h2].z, av[r][h2].w};
      split4(v, Ahi[r][h2], Alo[r][h2]);
    }
#pragma unroll
  for (int h2 = 0; h2 < 2; ++h2)
#pragma unroll
    for (int c = 0; c < 2; ++c) {
      float v[4] = {acc[h2][c][0], acc[h2][c][1], acc[h2][c][2], acc[h2][c][3]};
      split4(v, Bhi[h2][c], Blo[h2][c]);
    }
  facc n[2][2];
#pragma unroll
  for (int r = 0; r < 2; ++r)
#pragma unroll
    for (int c = 0; c < 2; ++c) {
      facc z;
#pragma unroll
      for (int j = 0; j < 4; ++j) z[j] = 0.0f;
#pragma unroll
      for (int h2 = 0; h2 < 2; ++h2) {
        z = MFMA16(Ahi[r][h2], Bhi[h2][c], z);
        z = MFMA16(Ahi[r][h2], Blo[h2][c], z);
        z = MFMA16(Alo[r][h2], Bhi[h2][c], z);
      }
      n[r][c] = z;
    }
#pragma unroll
  for (int r = 0; r < 2; ++r)
#pragma unroll
    for (int c = 0; c < 2; ++c) acc[r][c] = n[r][c];
}

// P = X * Y.  A[j*32+i] = X[i][j], Br[j*32+k] = Y[j][k]. Writes An[k*32+i] = P[i][k].
__device__ __forceinline__ void mm_step(const float* __restrict__ A,
                                        const float* __restrict__ Br,
                                        float* __restrict__ An, int lane) {
  const int i0 = (lane >> 3) << 2;
  const int k0 = (lane & 7) << 2;
  float acc[4][4];
#pragma unroll
  for (int r = 0; r < 4; ++r)
#pragma unroll
    for (int c = 0; c < 4; ++c) acc[r][c] = 0.0f;
#pragma unroll
  for (int j = 0; j < 32; ++j) {
    float4 av = *(const float4*)&A[j * 32 + i0];
    float4 bv = *(const float4*)&Br[j * 32 + k0];
    float af[4] = {av.x, av.y, av.z, av.w};
    float bf[4] = {bv.x, bv.y, bv.z, bv.w};
#pragma unroll
    for (int r = 0; r < 4; ++r)
#pragma unroll
      for (int c = 0; c < 4; ++c) acc[r][c] += af[r] * bf[c];
  }
#pragma unroll
  for (int c = 0; c < 4; ++c) {
    float4 wv = make_float4(acc[0][c], acc[1][c], acc[2][c], acc[3][c]);
    *(float4*)&An[(k0 + c) * 32 + i0] = wv;
  }
}

// ---------------------------------------------------------------------------
// K2 (fused): 128 blocks x 128 threads. Wave w folds chain 2b+w (16 segments,
// prefetched float4 fragments); LDS exchange; F = Right*Left; label contract.
// ---------------------------------------------------------------------------
__global__ __launch_bounds__(128) void finish_k(const float* __restrict__ ws,
                                                const float* __restrict__ label,
                                                float* __restrict__ out) {
  const int tid = threadIdx.x;
  const int lane = tid & 63;
  const int w = tid >> 6;  // 0 = left chain, 1 = right chain
  const int b = blockIdx.x;
  const int chain = 2 * b + w;
  const int col16 = lane & 15;
  const int q = lane >> 4;

  __shared__ float smL[1024];  // Left row-major:  smL[j*32+k] = L[j][k]
  __shared__ float smR[1024];  // Right col-major: smR[j*32+i] = R[i][j]
  __shared__ float smF[1024];  // smF[j*32+k] = F[k][j], F = R*L
  __shared__ float red[20];

  facc acc[2][2];
#pragma unroll
  for (int r = 0; r < 2; ++r)
#pragma unroll
    for (int c = 0; c < 2; ++c)
#pragma unroll
      for (int j = 0; j < 4; ++j)
        acc[r][c][j] = (16 * r + 4 * q + j == 16 * c + col16) ? 1.0f : 0.0f;

  const float* base = ws + (size_t)(chain * 16) * 1024;
  // A-fragment loads are contiguous float4 (segment products stored row-major):
  // av[r][h2] = S_t[16r+col16][16h2+4q .. +3]
  const int foff0 = (16 * 0 + col16) * 32;
  const int foff1 = (16 * 1 + col16) * 32;

  float4 av[2][2];
#pragma unroll
  for (int r = 0; r < 2; ++r)
#pragma unroll
    for (int h2 = 0; h2 < 2; ++h2)
      av[r][h2] = *(const float4*)&base[15 * 1024 + (r ? foff1 : foff0) + 16 * h2 + 4 * q];

  for (int t = 15; t > 0; --t) {
    float4 nav[2][2];
#pragma unroll
    for (int r = 0; r < 2; ++r)
#pragma unroll
      for (int h2 = 0; h2 < 2; ++h2)
        nav[r][h2] =
            *(const float4*)&base[(t - 1) * 1024 + (r ? foff1 : foff0) + 16 * h2 + 4 * q];
    fold_step(acc, av, t);
#pragma unroll
    for (int r = 0; r < 2; ++r)
#pragma unroll
      for (int h2 = 0; h2 < 2; ++h2) av[r][h2] = nav[r][h2];
  }
  fold_step(acc, av, 0);

  // write chain product to LDS in the layout mm_step wants
  if (w == 0) {
    // Left row-major: smL[row*32+col]
#pragma unroll
    for (int r = 0; r < 2; ++r)
#pragma unroll
      for (int c = 0; c < 2; ++c)
#pragma unroll
        for (int j = 0; j < 4; ++j)
          smL[(16 * r + 4 * q + j) * 32 + 16 * c + col16] = acc[r][c][j];
  } else {
    // Right col-major: smR[col*32+row] (float4: j contiguous in row)
#pragma unroll
    for (int r = 0; r < 2; ++r)
#pragma unroll
      for (int c = 0; c < 2; ++c)
        *(float4*)&smR[(16 * c + col16) * 32 + 16 * r + 4 * q] =
            make_float4(acc[r][c][0], acc[r][c][1], acc[r][c][2], acc[r][c][3]);
  }
  __syncthreads();

  if (w == 0) mm_step(smR, smL, smF, lane);  // smF[j*32+k] = F[k][j]
  __syncthreads();

  // score[l] = sum_e smF[e] * label[e*10+l], e = j*32+k
  float part[10];
#pragma unroll
  for (int l = 0; l < 10; ++l) part[l] = 0.0f;
#pragma unroll
  for (int u = 0; u < 8; ++u) {
    int e = tid + 128 * u;
    float v = smF[e];
    const float* lb = label + (size_t)e * 10;
#pragma unroll
    for (int l = 0; l < 10; ++l) part[l] += v * lb[l];
  }
#pragma unroll
  for (int l = 0; l < 10; ++l) {
#pragma unroll
    for (int o = 32; o > 0; o >>= 1) part[l] += __shfl_xor(part[l], o, 64);
  }
  if (lane == 0) {
#pragma unroll
    for (int l = 0; l < 10; ++l) red[w * 10 + l] = part[l];
  }
  __syncthreads();
  if (tid < 10) out[b * 10 + tid] = red[tid] + red[10 + tid];
}

extern "C" void kernel_launch(void* const* d_in, const int* in_sizes, int n_in,
                              void* d_out, int out_size, void* d_ws, size_t ws_size,
                              hipStream_t stream) {
  const float* x = (const float*)d_in[0];      // (128, 784)
  const float* core = (const float*)d_in[1];   // (784, 32, 32, 2)
  const float* label = (const float*)d_in[2];  // (32, 32, 10)
  float* out = (float*)d_out;                  // (128, 10)
  float* ws = (float*)d_ws;                    // 4096 slots x 1024 f = 16.78 MB

  hipLaunchKernelGGL(seg_mfma, dim3(1024), dim3(256), 0, stream, x, core, ws);
  hipLaunchKernelGGL(finish_k, dim3(128), dim3(128), 0, stream, ws, label, out);
}

// Round 5
// 160.913 us; speedup vs baseline: 1.3330x; 1.0253x over previous
//
#include <hip/hip_runtime.h>
#include <cstddef>

// MPS classifier: SIZE=784, D=32, DLOC=2, NUM_LABELS=10, LABEL_SITE=392, B=128
//
// Round-5 changes vs round 4 (seg 95us: latency-bound, 75% idle-issue, and the
// register prefetch was compiler-defeated — VGPR_Count 52 proves loads were
// sunk to use sites; finish_k ~60us: 16 serial folds, 128 blocks):
//  - seg: TLP instead of ILP. 2048 blocks x 128 thr, __launch_bounds__(128,8)
//    -> 32 waves/CU (was 12). No register prefetch (keeps VGPR<=64).
//  - seg: XCD-swizzled blockIdx so the 64 blocks sharing one (h,t) site stream
//    land on one XCD (bid%8 == combo%8) -> core fetched ~once per XCD.
//  - finish: 128 blocks x 512 thr; 8 waves each fold 4 segments (serial depth
//    8 total: 4 global folds + 4 LDS tree folds), then mm_step + label.

typedef short bfrag __attribute__((ext_vector_type(4)));   // 4 bf16
typedef float facc  __attribute__((ext_vector_type(4)));   // 4 fp32

#if !defined(__HIP_DEVICE_COMPILE__)
#define MFMA16(a, b, c) (c)  // host-pass stub (host clang lacks amdgcn builtins)
#elif __has_builtin(__builtin_amdgcn_mfma_f32_16x16x16bf16_1k)
#define MFMA16(a, b, c) __builtin_amdgcn_mfma_f32_16x16x16bf16_1k(a, b, c, 0, 0, 0)
#elif __has_builtin(__builtin_amdgcn_mfma_f32_16x16x16_bf16)
#define MFMA16(a, b, c) __builtin_amdgcn_mfma_f32_16x16x16_bf16(a, b, c, 0, 0, 0)
#else
#error "no 16x16x16 bf16 MFMA builtin on this target"
#endif

__device__ __forceinline__ short bf16h(float v) {
  unsigned u = __float_as_uint(v) + 0x8000u;  // round-half-up to bf16
  return (short)(u >> 16);
}

__device__ __forceinline__ bfrag pack4(const facc v) {
  bfrag r;
#pragma unroll
  for (int j = 0; j < 4; ++j) r[j] = bf16h(v[j]);
  return r;
}

// fp32 -> (hi bf16 rounded, lo bf16 of remainder)
__device__ __forceinline__ void split4(const float* v, bfrag& hi, bfrag& lo) {
#pragma unroll
  for (int j = 0; j < 4; ++j) {
    unsigned u = (__float_as_uint(v[j]) + 0x8000u) & 0xFFFF0000u;
    hi[j] = (short)(u >> 16);
    float lf = v[j] - __uint_as_float(u);
    lo[j] = bf16h(lf);
  }
}

// One site update: acc += E_s * bf16(acc).  acc[r][c][j] = P[16r+4q+j][16c+col16].
__device__ __forceinline__ void site_update(facc (&acc)[2][2],
                                            const float4 (&raw)[2][2][2],
                                            float xv, const float (&ds)[4]) {
  // snapshot B = bf16(P_old) BEFORE accumulation (C/D layout == B layout, K=16)
  bfrag B[2][2];
#pragma unroll
  for (int h2 = 0; h2 < 2; ++h2)
#pragma unroll
    for (int c = 0; c < 2; ++c) B[h2][c] = pack4(acc[h2][c]);

  bfrag A[2][2];
#pragma unroll
  for (int r = 0; r < 2; ++r)
#pragma unroll
    for (int h2 = 0; h2 < 2; ++h2) {
      float4 f0 = raw[r][h2][0];
      float4 f1 = raw[r][h2][1];
      float e0 = f0.x + xv * (f0.y - f0.x);
      float e1 = f0.z + xv * (f0.w - f0.z);
      float e2 = f1.x + xv * (f1.y - f1.x);
      float e3 = f1.z + xv * (f1.w - f1.z);
      if (r == h2) { e0 -= ds[0]; e1 -= ds[1]; e2 -= ds[2]; e3 -= ds[3]; }
      bfrag a; a[0] = bf16h(e0); a[1] = bf16h(e1); a[2] = bf16h(e2); a[3] = bf16h(e3);
      A[r][h2] = a;
    }

#pragma unroll
  for (int r = 0; r < 2; ++r)
#pragma unroll
    for (int c = 0; c < 2; ++c) {
      acc[r][c] = MFMA16(A[r][0], B[0][c], acc[r][c]);
      acc[r][c] = MFMA16(A[r][1], B[1][c], acc[r][c]);
    }
}

// ---------------------------------------------------------------------------
// K1: 2048 blocks x 128 threads (2 waves). Block = (h,t) combo x 2 batches.
// 8 waves/SIMD for latency hiding; XCD-swizzled block mapping.
// ---------------------------------------------------------------------------
__global__ __launch_bounds__(128, 8) void seg_mfma(const float* __restrict__ x,
                                                   const float* __restrict__ core,
                                                   float* __restrict__ ws) {
  const int lane = threadIdx.x & 63;
  const int w = threadIdx.x >> 6;
  const int col16 = lane & 15;
  const int q = lane >> 4;

  // bid = c1*512 + g*8 + c2 ; combo = c1*8 + c2 ; XCD(bid)=bid%8=combo%8
  const int bid = blockIdx.x;  // 0..2047
  const int c2 = bid & 7;
  const int g = (bid >> 3) & 63;
  const int c1 = bid >> 9;
  const int combo = c1 * 8 + c2;  // 0..31 = h*16 + t
  const int h = combo >> 4;
  const int t = combo & 15;
  const int b = g * 2 + w;

  const int start = (t < 8) ? 25 * t : 200 + 24 * (t - 8);
  const int len = (t < 8) ? 25 : 24;
  const int s_lo = h * 392 + start;
  const int s_hi = s_lo + len - 1;

  float ds[4];
#pragma unroll
  for (int j = 0; j < 4; ++j) ds[j] = (4 * q + j == col16) ? 1.0f : 0.0f;

  facc acc[2][2];
#pragma unroll
  for (int r = 0; r < 2; ++r)
#pragma unroll
    for (int c = 0; c < 2; ++c)
#pragma unroll
      for (int j = 0; j < 4; ++j)
        acc[r][c][j] = (16 * r + 4 * q + j == 16 * c + col16) ? 1.0f : 0.0f;

  // per-lane float4 offsets within a site block (512 float4s/site)
  int off[2][2][2];
#pragma unroll
  for (int r = 0; r < 2; ++r)
#pragma unroll
    for (int h2 = 0; h2 < 2; ++h2)
#pragma unroll
      for (int p = 0; p < 2; ++p)
        off[r][h2][p] = (16 * r + col16) * 16 + 8 * h2 + 2 * q + p;

  const float4* cp = (const float4*)core;
  const float* xb = x + b * 784;

  for (int s = s_hi; s >= s_lo; --s) {
    const size_t sb = (size_t)s * 512;
    float4 raw[2][2][2];
#pragma unroll
    for (int r = 0; r < 2; ++r)
#pragma unroll
      for (int h2 = 0; h2 < 2; ++h2)
#pragma unroll
        for (int p = 0; p < 2; ++p) raw[r][h2][p] = cp[sb + off[r][h2][p]];
    const float xv = xb[s];
    site_update(acc, raw, xv, ds);
  }

  // store segment product ROW-major: ws[slot + row*32 + col] = P[row][col]
  const size_t slot = (size_t)((b * 2 + h) * 16 + t) * 1024;
#pragma unroll
  for (int r = 0; r < 2; ++r)
#pragma unroll
    for (int c = 0; c < 2; ++c)
#pragma unroll
      for (int j = 0; j < 4; ++j)
        ws[slot + (size_t)(16 * r + 4 * q + j) * 32 + 16 * c + col16] = acc[r][c][j];
}

// One fold step: acc = S * acc (3-term bf16 hi/lo split).
// av[r][h2] = float4 of S[16r+col16][16h2+4q .. +3] (row-major source).
__device__ __forceinline__ void fold_step(facc (&acc)[2][2], const float4 (&av)[2][2]) {
  bfrag Ahi[2][2], Alo[2][2], Bhi[2][2], Blo[2][2];
#pragma unroll
  for (int r = 0; r < 2; ++r)
#pragma unroll
    for (int h2 = 0; h2 < 2; ++h2) {
      float v[4] = {av[r][h2].x, av[r][h2].y, av[r][h2].z, av[r][h2].w};
      split4(v, Ahi[r][h2], Alo[r][h2]);
    }
#pragma unroll
  for (int h2 = 0; h2 < 2; ++h2)
#pragma unroll
    for (int c = 0; c < 2; ++c) {
      float v[4] = {acc[h2][c][0], acc[h2][c][1], acc[h2][c][2], acc[h2][c][3]};
      split4(v, Bhi[h2][c], Blo[h2][c]);
    }
  facc n[2][2];
#pragma unroll
  for (int r = 0; r < 2; ++r)
#pragma unroll
    for (int c = 0; c < 2; ++c) {
      facc z;
#pragma unroll
      for (int j = 0; j < 4; ++j) z[j] = 0.0f;
#pragma unroll
      for (int h2 = 0; h2 < 2; ++h2) {
        z = MFMA16(Ahi[r][h2], Bhi[h2][c], z);
        z = MFMA16(Ahi[r][h2], Blo[h2][c], z);
        z = MFMA16(Alo[r][h2], Bhi[h2][c], z);
      }
      n[r][c] = z;
    }
#pragma unroll
  for (int r = 0; r < 2; ++r)
#pragma unroll
    for (int c = 0; c < 2; ++c) acc[r][c] = n[r][c];
}

// P = X * Y.  A[j*32+i] = X[i][j], Br[j*32+k] = Y[j][k]. Writes An[k*32+i] = P[i][k].
__device__ __forceinline__ void mm_step(const float* __restrict__ A,
                                        const float* __restrict__ Br,
                                        float* __restrict__ An, int lane) {
  const int i0 = (lane >> 3) << 2;
  const int k0 = (lane & 7) << 2;
  float acc[4][4];
#pragma unroll
  for (int r = 0; r < 4; ++r)
#pragma unroll
    for (int c = 0; c < 4; ++c) acc[r][c] = 0.0f;
#pragma unroll
  for (int j = 0; j < 32; ++j) {
    float4 av = *(const float4*)&A[j * 32 + i0];
    float4 bv = *(const float4*)&Br[j * 32 + k0];
    float af[4] = {av.x, av.y, av.z, av.w};
    float bf[4] = {bv.x, bv.y, bv.z, bv.w};
#pragma unroll
    for (int r = 0; r < 4; ++r)
#pragma unroll
      for (int c = 0; c < 4; ++c) acc[r][c] += af[r] * bf[c];
  }
#pragma unroll
  for (int c = 0; c < 4; ++c) {
    float4 wv = make_float4(acc[0][c], acc[1][c], acc[2][c], acc[3][c]);
    *(float4*)&An[(k0 + c) * 32 + i0] = wv;
  }
}

// ---------------------------------------------------------------------------
// K2 (fused finish): 128 blocks x 512 threads (8 waves).
// Wave wv: side = wv>>2 (0=left chain, 1=right), k = wv&3 folds segments
// [4k..4k+3] -> partial Q_k in LDS; wave k==0 tree-folds Q3..Q0; then
// F = Right*Left and label contraction.
// ---------------------------------------------------------------------------
__global__ __launch_bounds__(512) void finish_k(const float* __restrict__ ws,
                                                const float* __restrict__ label,
                                                float* __restrict__ out) {
  const int tid = threadIdx.x;
  const int lane = tid & 63;
  const int wv = tid >> 6;     // 0..7
  const int side = wv >> 2;    // 0 = left, 1 = right
  const int k = wv & 3;
  const int b = blockIdx.x;
  const int chain = 2 * b + side;
  const int col16 = lane & 15;
  const int q = lane >> 4;

  __shared__ float smQ[8][1024];  // partials, row-major
  __shared__ float smL[1024];     // Left row-major  (Br-form)
  __shared__ float smR[1024];     // Right col-major (A-form)
  __shared__ float smF[1024];     // smF[j*32+k] = F[k][j]
  __shared__ float red[80];

  facc acc[2][2];
#pragma unroll
  for (int r = 0; r < 2; ++r)
#pragma unroll
    for (int c = 0; c < 2; ++c)
#pragma unroll
      for (int j = 0; j < 4; ++j)
        acc[r][c][j] = (16 * r + 4 * q + j == 16 * c + col16) ? 1.0f : 0.0f;

  const float* base = ws + (size_t)(chain * 16) * 1024;
  const int fo0 = (16 * 0 + col16) * 32 + 4 * q;
  const int fo1 = (16 * 1 + col16) * 32 + 4 * q;

  // fold segments t = 4k+3 .. 4k (register prefetch depth 1)
  float4 av[2][2];
#pragma unroll
  for (int r = 0; r < 2; ++r)
#pragma unroll
    for (int h2 = 0; h2 < 2; ++h2)
      av[r][h2] = *(const float4*)&base[(4 * k + 3) * 1024 + (r ? fo1 : fo0) + 16 * h2];
  for (int t = 4 * k + 3; t > 4 * k; --t) {
    float4 nav[2][2];
#pragma unroll
    for (int r = 0; r < 2; ++r)
#pragma unroll
      for (int h2 = 0; h2 < 2; ++h2)
        nav[r][h2] = *(const float4*)&base[(t - 1) * 1024 + (r ? fo1 : fo0) + 16 * h2];
    fold_step(acc, av);
#pragma unroll
    for (int r = 0; r < 2; ++r)
#pragma unroll
      for (int h2 = 0; h2 < 2; ++h2) av[r][h2] = nav[r][h2];
  }
  fold_step(acc, av);

  // write partial Q_k row-major
#pragma unroll
  for (int r = 0; r < 2; ++r)
#pragma unroll
    for (int c = 0; c < 2; ++c)
#pragma unroll
      for (int j = 0; j < 4; ++j)
        smQ[wv][(16 * r + 4 * q + j) * 32 + 16 * c + col16] = acc[r][c][j];
  __syncthreads();

  // tree fold by wave k==0 of each side: acc = Q0*Q1*Q2*Q3
  if (k == 0) {
    facc a2[2][2];
#pragma unroll
    for (int r = 0; r < 2; ++r)
#pragma unroll
      for (int c = 0; c < 2; ++c)
#pragma unroll
        for (int j = 0; j < 4; ++j)
          a2[r][c][j] = (16 * r + 4 * q + j == 16 * c + col16) ? 1.0f : 0.0f;
    for (int kk = 3; kk >= 0; --kk) {
      float4 qv[2][2];
#pragma unroll
      for (int r = 0; r < 2; ++r)
#pragma unroll
        for (int h2 = 0; h2 < 2; ++h2)
          qv[r][h2] = *(const float4*)&smQ[side * 4 + kk][(r ? fo1 : fo0) + 16 * h2];
      fold_step(a2, qv);
    }
    if (side == 0) {
      // Left row-major (Br-form)
#pragma unroll
      for (int r = 0; r < 2; ++r)
#pragma unroll
        for (int c = 0; c < 2; ++c)
#pragma unroll
          for (int j = 0; j < 4; ++j)
            smL[(16 * r + 4 * q + j) * 32 + 16 * c + col16] = a2[r][c][j];
    } else {
      // Right col-major (A-form), j contiguous -> float4 store
#pragma unroll
      for (int r = 0; r < 2; ++r)
#pragma unroll
        for (int c = 0; c < 2; ++c)
          *(float4*)&smR[(16 * c + col16) * 32 + 16 * r + 4 * q] =
              make_float4(a2[r][c][0], a2[r][c][1], a2[r][c][2], a2[r][c][3]);
    }
  }
  __syncthreads();

  if (wv == 0) mm_step(smR, smL, smF, lane);  // smF[j*32+k] = F[k][j], F = R*L
  __syncthreads();

  // score[l] = sum_e smF[e] * label[e*10+l], e = j*32+k  (512 thr x 2 elems)
  float part[10];
#pragma unroll
  for (int l = 0; l < 10; ++l) part[l] = 0.0f;
#pragma unroll
  for (int u = 0; u < 2; ++u) {
    int e = tid + 512 * u;
    float v = smF[e];
    const float* lb = label + (size_t)e * 10;
#pragma unroll
    for (int l = 0; l < 10; ++l) part[l] += v * lb[l];
  }
#pragma unroll
  for (int l = 0; l < 10; ++l) {
#pragma unroll
    for (int o = 32; o > 0; o >>= 1) part[l] += __shfl_xor(part[l], o, 64);
  }
  if (lane == 0) {
#pragma unroll
    for (int l = 0; l < 10; ++l) red[wv * 10 + l] = part[l];
  }
  __syncthreads();
  if (tid < 10) {
    float s = 0.0f;
#pragma unroll
    for (int v = 0; v < 8; ++v) s += red[v * 10 + tid];
    out[b * 10 + tid] = s;
  }
}

extern "C" void kernel_launch(void* const* d_in, const int* in_sizes, int n_in,
                              void* d_out, int out_size, void* d_ws, size_t ws_size,
                              hipStream_t stream) {
  const float* x = (const float*)d_in[0];      // (128, 784)
  const float* core = (const float*)d_in[1];   // (784, 32, 32, 2)
  const float* label = (const float*)d_in[2];  // (32, 32, 10)
  float* out = (float*)d_out;                  // (128, 10)
  float* ws = (float*)d_ws;                    // 4096 slots x 1024 f = 16.78 MB

  hipLaunchKernelGGL(seg_mfma, dim3(2048), dim3(128), 0, stream, x, core, ws);
  hipLaunchKernelGGL(finish_k, dim3(128), dim3(512), 0, stream, ws, label, out);
}

// Round 6
// 104.185 us; speedup vs baseline: 2.0589x; 1.5445x over previous
//
#include <hip/hip_runtime.h>
#include <cstddef>

// MPS classifier: SIZE=784, D=32, DLOC=2, NUM_LABELS=10, LABEL_SITE=392, B=128
//
// Round-6: every hot-loop global access is now lane-coalesced.
//  - K0 xform_k: permute core (784 x 8KB) into fragment-major core2 so seg's
//    8 loads/site are contiguous 1KB wave loads (rounds 3-5 were pinned at
//    ~97us by scattered 2-lanes-per-line fragment loads; dur was invariant to
//    occupancy/prefetch/swizzle -> request-serialization, not latency/issue).
//  - seg_mfma: same math (acc += E*bf16(acc), B-feedback since C/D layout ==
//    B layout at K=16); loads from core2; stores segment product as A-form of
//    S^T (coalesced float4s).
//  - finish_k: transpose-world fold (chain^T = T15*...*T0), 128 blocks x 4
//    waves, coalesced prefetched A-frags, padded-LDS one-off exchanges.
// ws layout: [core2: 784*2048 f = 6.4MB][segments: 4096 * 1024 f = 16.8MB].

typedef short bfrag __attribute__((ext_vector_type(4)));   // 4 bf16
typedef float facc  __attribute__((ext_vector_type(4)));   // 4 fp32

#if !defined(__HIP_DEVICE_COMPILE__)
#define MFMA16(a, b, c) (c)  // host-pass stub (host clang lacks amdgcn builtins)
#elif __has_builtin(__builtin_amdgcn_mfma_f32_16x16x16bf16_1k)
#define MFMA16(a, b, c) __builtin_amdgcn_mfma_f32_16x16x16bf16_1k(a, b, c, 0, 0, 0)
#elif __has_builtin(__builtin_amdgcn_mfma_f32_16x16x16_bf16)
#define MFMA16(a, b, c) __builtin_amdgcn_mfma_f32_16x16x16_bf16(a, b, c, 0, 0, 0)
#else
#error "no 16x16x16 bf16 MFMA builtin on this target"
#endif

#define CORE2_FLOATS (784 * 2048)

__device__ __forceinline__ short bf16h(float v) {
  unsigned u = __float_as_uint(v) + 0x8000u;  // round-half-up to bf16
  return (short)(u >> 16);
}

__device__ __forceinline__ bfrag pack4(const facc v) {
  bfrag r;
#pragma unroll
  for (int j = 0; j < 4; ++j) r[j] = bf16h(v[j]);
  return r;
}

// fp32 -> (hi bf16 rounded, lo bf16 of remainder)
__device__ __forceinline__ void split4(const float* v, bfrag& hi, bfrag& lo) {
#pragma unroll
  for (int j = 0; j < 4; ++j) {
    unsigned u = (__float_as_uint(v[j]) + 0x8000u) & 0xFFFF0000u;
    hi[j] = (short)(u >> 16);
    float lf = v[j] - __uint_as_float(u);
    lo[j] = bf16h(lf);
  }
}

// ---------------------------------------------------------------------------
// K0: permute core into fragment-major layout.
// core2 float4 idx within site = ((r*2+h2)*2+p)*64 + lane  (lane = col16 + 16q)
// value = core float4 idx (16r+col16)*16 + 8*h2 + 2*q + p   (verbatim copy)
// ---------------------------------------------------------------------------
__global__ __launch_bounds__(256) void xform_k(const float* __restrict__ core,
                                               float* __restrict__ core2) {
  const int s = blockIdx.x;  // 784
  const int tid = threadIdx.x;
  const float4* src = (const float4*)(core + (size_t)s * 2048);
  float4* dst = (float4*)(core2 + (size_t)s * 2048);
#pragma unroll
  for (int u = 0; u < 2; ++u) {
    int o = tid + 256 * u;  // 0..511
    int lane = o & 63;
    int f = o >> 6;  // (r*2+h2)*2+p
    int p = f & 1;
    int h2 = (f >> 1) & 1;
    int r = f >> 2;
    int col16 = lane & 15;
    int q = lane >> 4;
    dst[o] = src[(16 * r + col16) * 16 + 8 * h2 + 2 * q + p];
  }
}

// One site update: acc += E_s * bf16(acc).  acc[r][c][j] = P[16r+4q+j][16c+col16].
__device__ __forceinline__ void site_update(facc (&acc)[2][2],
                                            const float4 (&raw)[2][2][2],
                                            float xv, const float (&ds)[4]) {
  // snapshot B = bf16(P_old) BEFORE accumulation (C/D layout == B layout, K=16)
  bfrag B[2][2];
#pragma unroll
  for (int h2 = 0; h2 < 2; ++h2)
#pragma unroll
    for (int c = 0; c < 2; ++c) B[h2][c] = pack4(acc[h2][c]);

  bfrag A[2][2];
#pragma unroll
  for (int r = 0; r < 2; ++r)
#pragma unroll
    for (int h2 = 0; h2 < 2; ++h2) {
      float4 f0 = raw[r][h2][0];
      float4 f1 = raw[r][h2][1];
      float e0 = f0.x + xv * (f0.y - f0.x);
      float e1 = f0.z + xv * (f0.w - f0.z);
      float e2 = f1.x + xv * (f1.y - f1.x);
      float e3 = f1.z + xv * (f1.w - f1.z);
      if (r == h2) { e0 -= ds[0]; e1 -= ds[1]; e2 -= ds[2]; e3 -= ds[3]; }
      bfrag a; a[0] = bf16h(e0); a[1] = bf16h(e1); a[2] = bf16h(e2); a[3] = bf16h(e3);
      A[r][h2] = a;
    }

#pragma unroll
  for (int r = 0; r < 2; ++r)
#pragma unroll
    for (int c = 0; c < 2; ++c) {
      acc[r][c] = MFMA16(A[r][0], B[0][c], acc[r][c]);
      acc[r][c] = MFMA16(A[r][1], B[1][c], acc[r][c]);
    }
}

// ---------------------------------------------------------------------------
// K1: 2048 blocks x 128 threads (2 waves = 2 batches). XCD-swizzled mapping.
// All global loads coalesced (core2 fragment-major).
// ---------------------------------------------------------------------------
__global__ __launch_bounds__(128, 8) void seg_mfma(const float* __restrict__ x,
                                                   const float* __restrict__ core2,
                                                   float* __restrict__ seg) {
  const int lane = threadIdx.x & 63;
  const int w = threadIdx.x >> 6;
  const int col16 = lane & 15;
  const int q = lane >> 4;

  // bid = c1*512 + g*8 + c2 ; combo = c1*8 + c2 ; XCD(bid)=bid%8=combo%8
  const int bid = blockIdx.x;  // 0..2047
  const int c2 = bid & 7;
  const int g = (bid >> 3) & 63;
  const int c1 = bid >> 9;
  const int combo = c1 * 8 + c2;  // 0..31 = h*16 + t
  const int h = combo >> 4;
  const int t = combo & 15;
  const int b = g * 2 + w;

  const int start = (t < 8) ? 25 * t : 200 + 24 * (t - 8);
  const int len = (t < 8) ? 25 : 24;
  const int s_lo = h * 392 + start;
  const int s_hi = s_lo + len - 1;

  float ds[4];
#pragma unroll
  for (int j = 0; j < 4; ++j) ds[j] = (4 * q + j == col16) ? 1.0f : 0.0f;

  facc acc[2][2];
#pragma unroll
  for (int r = 0; r < 2; ++r)
#pragma unroll
    for (int c = 0; c < 2; ++c)
#pragma unroll
      for (int j = 0; j < 4; ++j)
        acc[r][c][j] = (16 * r + 4 * q + j == 16 * c + col16) ? 1.0f : 0.0f;

  const float4* cp = (const float4*)core2;
  const float* xb = x + b * 784;

  for (int s = s_hi; s >= s_lo; --s) {
    const size_t sb = (size_t)s * 512;
    float4 raw[2][2][2];
#pragma unroll
    for (int r = 0; r < 2; ++r)
#pragma unroll
      for (int h2 = 0; h2 < 2; ++h2)
#pragma unroll
        for (int p = 0; p < 2; ++p)
          raw[r][h2][p] = cp[sb + ((r * 2 + h2) * 2 + p) * 64 + lane];
    const float xv = xb[s];
    site_update(acc, raw, xv, ds);
  }

  // Store A-form of S^T (fragment-major, coalesced):
  //   stored frag (R,H), lane, j  =  S^T[16R+col16][16H+4q+j] = acc[H][R][j]
  float4* o = (float4*)(seg + (size_t)((b * 2 + h) * 16 + t) * 1024);
#pragma unroll
  for (int R = 0; R < 2; ++R)
#pragma unroll
    for (int H = 0; H < 2; ++H)
      o[(R * 2 + H) * 64 + lane] =
          make_float4(acc[H][R][0], acc[H][R][1], acc[H][R][2], acc[H][R][3]);
}

// One fold step: acc <- A * acc (3-term bf16 hi/lo split).
// av[R][H] = float4 A-frag: A[16R+col16][16H+4q .. +3].
__device__ __forceinline__ void fold_step(facc (&acc)[2][2], const float4 (&av)[2][2]) {
  bfrag Ahi[2][2], Alo[2][2], Bhi[2][2], Blo[2][2];
#pragma unroll
  for (int R = 0; R < 2; ++R)
#pragma unroll
    for (int H = 0; H < 2; ++H) {
      float v[4] = {av[R][H].x, av[R][H].y, av[R][H].z, av[R][H].w};
      split4(v, Ahi[R][H], Alo[R][H]);
    }
#pragma unroll
  for (int H = 0; H < 2; ++H)
#pragma unroll
    for (int c = 0; c < 2; ++c) {
      float v[4] = {acc[H][c][0], acc[H][c][1], acc[H][c][2], acc[H][c][3]};
      split4(v, Bhi[H][c], Blo[H][c]);
    }
  facc n[2][2];
#pragma unroll
  for (int R = 0; R < 2; ++R)
#pragma unroll
    for (int c = 0; c < 2; ++c) {
      facc z;
#pragma unroll
      for (int j = 0; j < 4; ++j) z[j] = 0.0f;
#pragma unroll
      for (int H = 0; H < 2; ++H) {
        z = MFMA16(Ahi[R][H], Bhi[H][c], z);
        z = MFMA16(Ahi[R][H], Blo[H][c], z);
        z = MFMA16(Alo[R][H], Bhi[H][c], z);
      }
      n[R][c] = z;
    }
#pragma unroll
  for (int R = 0; R < 2; ++R)
#pragma unroll
    for (int c = 0; c < 2; ++c) acc[R][c] = n[R][c];
}

// ---------------------------------------------------------------------------
// K2: 128 blocks x 256 threads (4 waves). Transpose-world:
//   T_t = S_t^T stored in A-form; chain^T = T15*...*T0.
//   wave (side, half): folds t = half*8 .. half*8+7 ascending -> X_{side,half}
//   combine: X1 (from LDS, padded) * X0  -> chain^T per side
//   H = Left^T * Right^T ; score_l = sum_jk H[j][k] label[j][k][l]
// ---------------------------------------------------------------------------
__global__ __launch_bounds__(256) void finish_k(const float* __restrict__ seg,
                                                const float* __restrict__ label,
                                                float* __restrict__ out) {
  const int tid = threadIdx.x;
  const int lane = tid & 63;
  const int wv = tid >> 6;    // 0..3
  const int side = wv >> 1;   // 0 = left chain, 1 = right chain
  const int half = wv & 1;
  const int b = blockIdx.x;
  const int chain = 2 * b + side;
  const int col16 = lane & 15;
  const int q = lane >> 4;

  __shared__ float smX[2][32 * 36];  // padded row-major exchange (stride 36)
  __shared__ float smF[1024];        // H row-major
  __shared__ float red[40];

  facc acc[2][2];
#pragma unroll
  for (int r = 0; r < 2; ++r)
#pragma unroll
    for (int c = 0; c < 2; ++c)
#pragma unroll
      for (int j = 0; j < 4; ++j)
        acc[r][c][j] = (16 * r + 4 * q + j == 16 * c + col16) ? 1.0f : 0.0f;

  const float* base = seg + (size_t)(chain * 16) * 1024;
  const int t0 = half * 8;

  // fold 8 segments, coalesced A-frag loads, register prefetch depth 1
  float4 av[2][2];
#pragma unroll
  for (int R = 0; R < 2; ++R)
#pragma unroll
    for (int H = 0; H < 2; ++H)
      av[R][H] = *(const float4*)&base[(size_t)t0 * 1024 + ((R * 2 + H) * 64 + lane) * 4];
  for (int t = t0; t < t0 + 7; ++t) {
    float4 nav[2][2];
#pragma unroll
    for (int R = 0; R < 2; ++R)
#pragma unroll
      for (int H = 0; H < 2; ++H)
        nav[R][H] =
            *(const float4*)&base[(size_t)(t + 1) * 1024 + ((R * 2 + H) * 64 + lane) * 4];
    fold_step(acc, av);
#pragma unroll
    for (int R = 0; R < 2; ++R)
#pragma unroll
      for (int H = 0; H < 2; ++H) av[R][H] = nav[R][H];
  }
  fold_step(acc, av);  // acc = X_{side,half} = T_{t0+7}*...*T_{t0}

  // exchange X1 (padded row-major), combine into half==0 waves
  if (half == 1) {
#pragma unroll
    for (int r = 0; r < 2; ++r)
#pragma unroll
      for (int c = 0; c < 2; ++c)
#pragma unroll
        for (int j = 0; j < 4; ++j)
          smX[side][(16 * r + 4 * q + j) * 36 + 16 * c + col16] = acc[r][c][j];
  }
  __syncthreads();
  if (half == 0) {
    float4 qv[2][2];
#pragma unroll
    for (int R = 0; R < 2; ++R)
#pragma unroll
      for (int H = 0; H < 2; ++H)
        qv[R][H] = *(const float4*)&smX[side][(16 * R + col16) * 36 + 16 * H + 4 * q];
    fold_step(acc, qv);  // acc = X1 * X0 = chain^T  (LeftT on wv0, RightT on wv2)
  }
  __syncthreads();

  // H = LeftT * RightT : wv0 publishes LeftT (padded), wv2 computes
  if (wv == 0) {
#pragma unroll
    for (int r = 0; r < 2; ++r)
#pragma unroll
      for (int c = 0; c < 2; ++c)
#pragma unroll
        for (int j = 0; j < 4; ++j)
          smX[0][(16 * r + 4 * q + j) * 36 + 16 * c + col16] = acc[r][c][j];
  }
  __syncthreads();
  if (wv == 2) {
    float4 qv[2][2];
#pragma unroll
    for (int R = 0; R < 2; ++R)
#pragma unroll
      for (int H = 0; H < 2; ++H)
        qv[R][H] = *(const float4*)&smX[0][(16 * R + col16) * 36 + 16 * H + 4 * q];
    fold_step(acc, qv);  // acc = LeftT * RightT = H
    // H[j][k]: row j = 16r+4q+jj, col k = 16c+col16 -> smF[j*32+k]
#pragma unroll
    for (int r = 0; r < 2; ++r)
#pragma unroll
      for (int c = 0; c < 2; ++c)
#pragma unroll
        for (int j = 0; j < 4; ++j)
          smF[(16 * r + 4 * q + j) * 32 + 16 * c + col16] = acc[r][c][j];
  }
  __syncthreads();

  // score[l] = sum_e smF[e] * label[e*10+l]
  float part[10];
#pragma unroll
  for (int l = 0; l < 10; ++l) part[l] = 0.0f;
#pragma unroll
  for (int u = 0; u < 4; ++u) {
    int e = tid + 256 * u;
    float v = smF[e];
    const float* lb = label + (size_t)e * 10;
#pragma unroll
    for (int l = 0; l < 10; ++l) part[l] += v * lb[l];
  }
#pragma unroll
  for (int l = 0; l < 10; ++l) {
#pragma unroll
    for (int o = 32; o > 0; o >>= 1) part[l] += __shfl_xor(part[l], o, 64);
  }
  if (lane == 0) {
#pragma unroll
    for (int l = 0; l < 10; ++l) red[wv * 10 + l] = part[l];
  }
  __syncthreads();
  if (tid < 10) {
    float s = 0.0f;
#pragma unroll
    for (int v = 0; v < 4; ++v) s += red[v * 10 + tid];
    out[b * 10 + tid] = s;
  }
}

extern "C" void kernel_launch(void* const* d_in, const int* in_sizes, int n_in,
                              void* d_out, int out_size, void* d_ws, size_t ws_size,
                              hipStream_t stream) {
  const float* x = (const float*)d_in[0];      // (128, 784)
  const float* core = (const float*)d_in[1];   // (784, 32, 32, 2)
  const float* label = (const float*)d_in[2];  // (32, 32, 10)
  float* out = (float*)d_out;                  // (128, 10)
  float* ws = (float*)d_ws;                    // needs 23.2 MB

  float* core2 = ws;                  // 784*2048 floats = 6.4 MB
  float* seg = ws + CORE2_FLOATS;     // 4096 slots x 1024 floats = 16.8 MB

  hipLaunchKernelGGL(xform_k, dim3(784), dim3(256), 0, stream, core, core2);
  hipLaunchKernelGGL(seg_mfma, dim3(2048), dim3(128), 0, stream, x, core2, seg);
  hipLaunchKernelGGL(finish_k, dim3(128), dim3(256), 0, stream, seg, label, out);
}

// Round 7
// 95.742 us; speedup vs baseline: 2.2404x; 1.0882x over previous
//
#include <hip/hip_runtime.h>
#include <cstddef>

// MPS classifier: SIZE=784, D=32, DLOC=2, NUM_LABELS=10, LABEL_SITE=392, B=128
//
// Round-7: halve seg's bytes and VALU.
//  - xform_k now emits bf16 pairs (e0 = M0 - I, d = M1 - M0), one dword per
//    element (d in hi16, e0 in lo16), fragment-major. Per site per wave: 4
//    coalesced dwordx4 loads carry BOTH blend operands (was 8 loads of fp32).
//    Unpack = shl/and (bf16->f32 is a shift); blend = 1 FMA; diagonal
//    subtraction is pre-folded into e0.
//  - seg_mfma: 1024 blocks x 256 thr (4 batches/block -> same-site L1 reuse),
//    XCD-swizzled; math unchanged: acc += E*bf16(acc), B-operand feedback
//    (C/D layout == B layout for K=16 MFMA).
//  - finish_k: unchanged from round 6 (transpose-world fold).
// ws: [core2b: 784*1024 dwords = 3.2MB][segments: 4096 * 1024 f = 16.8MB].

typedef short bfrag __attribute__((ext_vector_type(4)));   // 4 bf16
typedef float facc  __attribute__((ext_vector_type(4)));   // 4 fp32

#if !defined(__HIP_DEVICE_COMPILE__)
#define MFMA16(a, b, c) (c)  // host-pass stub (host clang lacks amdgcn builtins)
#elif __has_builtin(__builtin_amdgcn_mfma_f32_16x16x16bf16_1k)
#define MFMA16(a, b, c) __builtin_amdgcn_mfma_f32_16x16x16bf16_1k(a, b, c, 0, 0, 0)
#elif __has_builtin(__builtin_amdgcn_mfma_f32_16x16x16_bf16)
#define MFMA16(a, b, c) __builtin_amdgcn_mfma_f32_16x16x16_bf16(a, b, c, 0, 0, 0)
#else
#error "no 16x16x16 bf16 MFMA builtin on this target"
#endif

#define CORE2B_DWORDS (784 * 1024)

__device__ __forceinline__ short bf16h(float v) {
  unsigned u = __float_as_uint(v) + 0x8000u;  // round-half-up to bf16
  return (short)(u >> 16);
}

__device__ __forceinline__ bfrag pack4(const facc v) {
  bfrag r;
#pragma unroll
  for (int j = 0; j < 4; ++j) r[j] = bf16h(v[j]);
  return r;
}

// fp32 -> (hi bf16 rounded, lo bf16 of remainder)
__device__ __forceinline__ void split4(const float* v, bfrag& hi, bfrag& lo) {
#pragma unroll
  for (int j = 0; j < 4; ++j) {
    unsigned u = (__float_as_uint(v[j]) + 0x8000u) & 0xFFFF0000u;
    hi[j] = (short)(u >> 16);
    float lf = v[j] - __uint_as_float(u);
    lo[j] = bf16h(lf);
  }
}

// ---------------------------------------------------------------------------
// K0: core -> core2b. Per site, 1024 dwords, fragment-major:
//   dword idx = (f*64 + lane)*4 + j,  f = r*2+h2, lane = col16 + 16q
//   element (i = 16r+col16, col = 16h2+4q+j)
//   dword = (bf16(M1-M0) << 16) | bf16(M0 - I)
// 784 blocks x 256 threads; thread = (f, lane).
// ---------------------------------------------------------------------------
__global__ __launch_bounds__(256) void xform_k(const float* __restrict__ core,
                                               unsigned* __restrict__ core2b) {
  const int s = blockIdx.x;  // 0..783
  const int tid = threadIdx.x;
  const int f = tid >> 6;
  const int lane = tid & 63;
  const int col16 = lane & 15;
  const int q = lane >> 4;
  const int r = f >> 1;
  const int h2 = f & 1;
  const int i = 16 * r + col16;
  const int c0 = 16 * h2 + 4 * q;  // col of j=0

  const float* src = core + (size_t)s * 2048 + ((size_t)i * 32 + c0) * 2;
  float4 v0 = *(const float4*)(src);      // (m0,m1) for j=0,1
  float4 v1 = *(const float4*)(src + 4);  // (m0,m1) for j=2,3

  unsigned w[4];
  {
    float m0[4] = {v0.x, v0.z, v1.x, v1.z};
    float m1[4] = {v0.y, v0.w, v1.y, v1.w};
#pragma unroll
    for (int j = 0; j < 4; ++j) {
      float e0 = m0[j] - ((i == c0 + j) ? 1.0f : 0.0f);
      float d = m1[j] - m0[j];
      w[j] = ((unsigned)(unsigned short)bf16h(d) << 16) |
             (unsigned)(unsigned short)bf16h(e0);
    }
  }
  *(uint4*)(core2b + (size_t)s * 1024 + (size_t)tid * 4) =
      make_uint4(w[0], w[1], w[2], w[3]);
}

// ---------------------------------------------------------------------------
// K1: 1024 blocks x 256 threads (4 waves = 4 batches, same site stream).
// Per site: 4 coalesced dwordx4 loads; unpack shl/and + 1 FMA; 8 MFMA.
// ---------------------------------------------------------------------------
__global__ __launch_bounds__(256, 4) void seg_mfma(const float* __restrict__ x,
                                                   const unsigned* __restrict__ core2b,
                                                   float* __restrict__ seg) {
  const int lane = threadIdx.x & 63;
  const int w = threadIdx.x >> 6;
  const int col16 = lane & 15;
  const int q = lane >> 4;

  // bid = c1*256 + g*8 + c2 ; combo = c1*8 + c2 ; XCD(bid)=bid%8=combo%8
  const int bid = blockIdx.x;  // 0..1023
  const int c2 = bid & 7;
  const int g = (bid >> 3) & 31;
  const int c1 = bid >> 8;
  const int combo = c1 * 8 + c2;  // 0..31 = h*16 + t
  const int h = combo >> 4;
  const int t = combo & 15;
  const int b = g * 4 + w;

  const int start = (t < 8) ? 25 * t : 200 + 24 * (t - 8);
  const int len = (t < 8) ? 25 : 24;
  const int s_lo = h * 392 + start;
  const int s_hi = s_lo + len - 1;

  facc acc[2][2];
#pragma unroll
  for (int r = 0; r < 2; ++r)
#pragma unroll
    for (int c = 0; c < 2; ++c)
#pragma unroll
      for (int j = 0; j < 4; ++j)
        acc[r][c][j] = (16 * r + 4 * q + j == 16 * c + col16) ? 1.0f : 0.0f;

  const uint4* cp = (const uint4*)core2b;
  const float* xb = x + b * 784;

  for (int s = s_hi; s >= s_lo; --s) {
    uint4 raw[4];  // frag f = r*2+h2
#pragma unroll
    for (int f = 0; f < 4; ++f) raw[f] = cp[(size_t)s * 256 + f * 64 + lane];
    const float xv = xb[s];

    // B = bf16(P_old) BEFORE accumulation
    bfrag B[2][2];
#pragma unroll
    for (int h2 = 0; h2 < 2; ++h2)
#pragma unroll
      for (int c = 0; c < 2; ++c) B[h2][c] = pack4(acc[h2][c]);

    // A = E fragments: e = e0 + xv*d (bf16 inputs, fp32 fma, bf16 round)
    bfrag A[2][2];
#pragma unroll
    for (int r = 0; r < 2; ++r)
#pragma unroll
      for (int h2 = 0; h2 < 2; ++h2) {
        unsigned wd[4] = {raw[r * 2 + h2].x, raw[r * 2 + h2].y, raw[r * 2 + h2].z,
                          raw[r * 2 + h2].w};
        bfrag a;
#pragma unroll
        for (int j = 0; j < 4; ++j) {
          float e0 = __uint_as_float(wd[j] << 16);
          float d = __uint_as_float(wd[j] & 0xFFFF0000u);
          a[j] = bf16h(fmaf(xv, d, e0));
        }
        A[r][h2] = a;
      }

#pragma unroll
    for (int r = 0; r < 2; ++r)
#pragma unroll
      for (int c = 0; c < 2; ++c) {
        acc[r][c] = MFMA16(A[r][0], B[0][c], acc[r][c]);
        acc[r][c] = MFMA16(A[r][1], B[1][c], acc[r][c]);
      }
  }

  // Store A-form of S^T (fragment-major, coalesced):
  //   frag (R,H), lane, j  =  S^T[16R+col16][16H+4q+j] = acc[H][R][j]
  float4* o = (float4*)(seg + (size_t)((b * 2 + h) * 16 + t) * 1024);
#pragma unroll
  for (int R = 0; R < 2; ++R)
#pragma unroll
    for (int H = 0; H < 2; ++H)
      o[(R * 2 + H) * 64 + lane] =
          make_float4(acc[H][R][0], acc[H][R][1], acc[H][R][2], acc[H][R][3]);
}

// One fold step: acc <- A * acc (3-term bf16 hi/lo split).
// av[R][H] = float4 A-frag: A[16R+col16][16H+4q .. +3].
__device__ __forceinline__ void fold_step(facc (&acc)[2][2], const float4 (&av)[2][2]) {
  bfrag Ahi[2][2], Alo[2][2], Bhi[2][2], Blo[2][2];
#pragma unroll
  for (int R = 0; R < 2; ++R)
#pragma unroll
    for (int H = 0; H < 2; ++H) {
      float v[4] = {av[R][H].x, av[R][H].y, av[R][H].z, av[R][H].w};
      split4(v, Ahi[R][H], Alo[R][H]);
    }
#pragma unroll
  for (int H = 0; H < 2; ++H)
#pragma unroll
    for (int c = 0; c < 2; ++c) {
      float v[4] = {acc[H][c][0], acc[H][c][1], acc[H][c][2], acc[H][c][3]};
      split4(v, Bhi[H][c], Blo[H][c]);
    }
  facc n[2][2];
#pragma unroll
  for (int R = 0; R < 2; ++R)
#pragma unroll
    for (int c = 0; c < 2; ++c) {
      facc z;
#pragma unroll
      for (int j = 0; j < 4; ++j) z[j] = 0.0f;
#pragma unroll
      for (int H = 0; H < 2; ++H) {
        z = MFMA16(Ahi[R][H], Bhi[H][c], z);
        z = MFMA16(Ahi[R][H], Blo[H][c], z);
        z = MFMA16(Alo[R][H], Bhi[H][c], z);
      }
      n[R][c] = z;
    }
#pragma unroll
  for (int R = 0; R < 2; ++R)
#pragma unroll
    for (int c = 0; c < 2; ++c) acc[R][c] = n[R][c];
}

// ---------------------------------------------------------------------------
// K2: 128 blocks x 256 threads (4 waves). Transpose-world:
//   T_t = S_t^T stored in A-form; chain^T = T15*...*T0.
//   wave (side, half): folds t = half*8 .. half*8+7 ascending -> X_{side,half}
//   combine: X1 * X0 -> chain^T per side; H = Left^T * Right^T; label contract.
// ---------------------------------------------------------------------------
__global__ __launch_bounds__(256) void finish_k(const float* __restrict__ seg,
                                                const float* __restrict__ label,
                                                float* __restrict__ out) {
  const int tid = threadIdx.x;
  const int lane = tid & 63;
  const int wv = tid >> 6;    // 0..3
  const int side = wv >> 1;   // 0 = left chain, 1 = right chain
  const int half = wv & 1;
  const int b = blockIdx.x;
  const int chain = 2 * b + side;
  const int col16 = lane & 15;
  const int q = lane >> 4;

  __shared__ float smX[2][32 * 36];  // padded row-major exchange (stride 36)
  __shared__ float smF[1024];        // H row-major
  __shared__ float red[40];

  facc acc[2][2];
#pragma unroll
  for (int r = 0; r < 2; ++r)
#pragma unroll
    for (int c = 0; c < 2; ++c)
#pragma unroll
      for (int j = 0; j < 4; ++j)
        acc[r][c][j] = (16 * r + 4 * q + j == 16 * c + col16) ? 1.0f : 0.0f;

  const float* base = seg + (size_t)(chain * 16) * 1024;
  const int t0 = half * 8;

  // fold 8 segments, coalesced A-frag loads, register prefetch depth 1
  float4 av[2][2];
#pragma unroll
  for (int R = 0; R < 2; ++R)
#pragma unroll
    for (int H = 0; H < 2; ++H)
      av[R][H] = *(const float4*)&base[(size_t)t0 * 1024 + ((R * 2 + H) * 64 + lane) * 4];
  for (int t = t0; t < t0 + 7; ++t) {
    float4 nav[2][2];
#pragma unroll
    for (int R = 0; R < 2; ++R)
#pragma unroll
      for (int H = 0; H < 2; ++H)
        nav[R][H] =
            *(const float4*)&base[(size_t)(t + 1) * 1024 + ((R * 2 + H) * 64 + lane) * 4];
    fold_step(acc, av);
#pragma unroll
    for (int R = 0; R < 2; ++R)
#pragma unroll
      for (int H = 0; H < 2; ++H) av[R][H] = nav[R][H];
  }
  fold_step(acc, av);  // acc = X_{side,half}

  // exchange X1 (padded row-major), combine into half==0 waves
  if (half == 1) {
#pragma unroll
    for (int r = 0; r < 2; ++r)
#pragma unroll
      for (int c = 0; c < 2; ++c)
#pragma unroll
        for (int j = 0; j < 4; ++j)
          smX[side][(16 * r + 4 * q + j) * 36 + 16 * c + col16] = acc[r][c][j];
  }
  __syncthreads();
  if (half == 0) {
    float4 qv[2][2];
#pragma unroll
    for (int R = 0; R < 2; ++R)
#pragma unroll
      for (int H = 0; H < 2; ++H)
        qv[R][H] = *(const float4*)&smX[side][(16 * R + col16) * 36 + 16 * H + 4 * q];
    fold_step(acc, qv);  // acc = X1 * X0 = chain^T (LeftT on wv0, RightT on wv2)
  }
  __syncthreads();

  // H = LeftT * RightT : wv0 publishes LeftT (padded), wv2 computes
  if (wv == 0) {
#pragma unroll
    for (int r = 0; r < 2; ++r)
#pragma unroll
      for (int c = 0; c < 2; ++c)
#pragma unroll
        for (int j = 0; j < 4; ++j)
          smX[0][(16 * r + 4 * q + j) * 36 + 16 * c + col16] = acc[r][c][j];
  }
  __syncthreads();
  if (wv == 2) {
    float4 qv[2][2];
#pragma unroll
    for (int R = 0; R < 2; ++R)
#pragma unroll
      for (int H = 0; H < 2; ++H)
        qv[R][H] = *(const float4*)&smX[0][(16 * R + col16) * 36 + 16 * H + 4 * q];
    fold_step(acc, qv);  // acc = LeftT * RightT = H
#pragma unroll
    for (int r = 0; r < 2; ++r)
#pragma unroll
      for (int c = 0; c < 2; ++c)
#pragma unroll
        for (int j = 0; j < 4; ++j)
          smF[(16 * r + 4 * q + j) * 32 + 16 * c + col16] = acc[r][c][j];
  }
  __syncthreads();

  // score[l] = sum_e smF[e] * label[e*10+l]
  float part[10];
#pragma unroll
  for (int l = 0; l < 10; ++l) part[l] = 0.0f;
#pragma unroll
  for (int u = 0; u < 4; ++u) {
    int e = tid + 256 * u;
    float v = smF[e];
    const float* lb = label + (size_t)e * 10;
#pragma unroll
    for (int l = 0; l < 10; ++l) part[l] += v * lb[l];
  }
#pragma unroll
  for (int l = 0; l < 10; ++l) {
#pragma unroll
    for (int o = 32; o > 0; o >>= 1) part[l] += __shfl_xor(part[l], o, 64);
  }
  if (lane == 0) {
#pragma unroll
    for (int l = 0; l < 10; ++l) red[wv * 10 + l] = part[l];
  }
  __syncthreads();
  if (tid < 10) {
    float s = 0.0f;
#pragma unroll
    for (int v = 0; v < 4; ++v) s += red[v * 10 + tid];
    out[b * 10 + tid] = s;
  }
}

extern "C" void kernel_launch(void* const* d_in, const int* in_sizes, int n_in,
                              void* d_out, int out_size, void* d_ws, size_t ws_size,
                              hipStream_t stream) {
  const float* x = (const float*)d_in[0];      // (128, 784)
  const float* core = (const float*)d_in[1];   // (784, 32, 32, 2)
  const float* label = (const float*)d_in[2];  // (32, 32, 10)
  float* out = (float*)d_out;                  // (128, 10)

  unsigned* core2b = (unsigned*)d_ws;                    // 3.2 MB
  float* seg = (float*)d_ws + CORE2B_DWORDS;             // 16.8 MB

  hipLaunchKernelGGL(xform_k, dim3(784), dim3(256), 0, stream, core, core2b);
  hipLaunchKernelGGL(seg_mfma, dim3(1024), dim3(256), 0, stream, x, core2b, seg);
  hipLaunchKernelGGL(finish_k, dim3(128), dim3(256), 0, stream, seg, label, out);
}

// Round 9
// 93.251 us; speedup vs baseline: 2.3003x; 1.0267x over previous
//
#include <hip/hip_runtime.h>
#include <cstddef>

// MPS classifier: SIZE=784, D=32, DLOC=2, NUM_LABELS=10, LABEL_SITE=392, B=128
//
// Round-9 = round-8 with the tree-fold transpose bug fixed:
//  - kchain's own-segment LDS publish now stores T_k = S_k^T (fragment-level
//    index swap, float4 store), so the ascending LDS tree fold computes
//    T_{k+1}*T_k = (S_k*S_{k+1})^T — matching the verified round-7 T-world
//    semantics. Round 8 wrote S_k row-major -> order-reversed product
//    (absmax 3.875).
//  - xform_k: coalesced-read/scatter-write core -> core2b (bf16 pair
//    (e0=M0-I, d=M1-M0) per dword, fragment-major).
//  - kchain: 512 blocks x 512 thr = (chain, half). 8 waves run one segment
//    site-loop each (acc += E*bf16(acc), B-feedback), then 3-level LDS tree
//    fold (padded stride-36) -> half-chain product X stored row-major (2MB).
//  - gfin: 128 blocks x 64 thr: H = X_L1*X_L0*X_R1*X_R0 = Left^T*Right^T,
//    then label contraction.
// ws: [core2b 3.2MB][halfbuf 512*1024 f = 2MB].

typedef short bfrag __attribute__((ext_vector_type(4)));   // 4 bf16
typedef float facc  __attribute__((ext_vector_type(4)));   // 4 fp32

#if !defined(__HIP_DEVICE_COMPILE__)
#define MFMA16(a, b, c) (c)  // host-pass stub (host clang lacks amdgcn builtins)
#elif __has_builtin(__builtin_amdgcn_mfma_f32_16x16x16bf16_1k)
#define MFMA16(a, b, c) __builtin_amdgcn_mfma_f32_16x16x16bf16_1k(a, b, c, 0, 0, 0)
#elif __has_builtin(__builtin_amdgcn_mfma_f32_16x16x16_bf16)
#define MFMA16(a, b, c) __builtin_amdgcn_mfma_f32_16x16x16_bf16(a, b, c, 0, 0, 0)
#else
#error "no 16x16x16 bf16 MFMA builtin on this target"
#endif

#define CORE2B_DWORDS (784 * 1024)

__device__ __forceinline__ short bf16h(float v) {
  unsigned u = __float_as_uint(v) + 0x8000u;  // round-half-up to bf16
  return (short)(u >> 16);
}

// pack 4 fp32 -> 4 bf16 (HW cvt_pk on gfx950, manual fallback)
#if defined(__HIP_DEVICE_COMPILE__) && __has_builtin(__builtin_amdgcn_cvt_pk_bf16_f32)
typedef __bf16 bf16x2 __attribute__((ext_vector_type(2)));
__device__ __forceinline__ bfrag packf4(float a, float b, float c, float d) {
  bf16x2 lo = __builtin_amdgcn_cvt_pk_bf16_f32(a, b);
  bf16x2 hi = __builtin_amdgcn_cvt_pk_bf16_f32(c, d);
  uint2 u = make_uint2(__builtin_bit_cast(unsigned, lo), __builtin_bit_cast(unsigned, hi));
  return __builtin_bit_cast(bfrag, u);
}
#else
__device__ __forceinline__ bfrag packf4(float a, float b, float c, float d) {
  bfrag r; r[0] = bf16h(a); r[1] = bf16h(b); r[2] = bf16h(c); r[3] = bf16h(d);
  return r;
}
#endif

__device__ __forceinline__ bfrag pack4(const facc v) {
  return packf4(v[0], v[1], v[2], v[3]);
}

// fp32 -> (hi bf16 rounded, lo bf16 of remainder) — cold path (folds only)
__device__ __forceinline__ void split4(const float* v, bfrag& hi, bfrag& lo) {
#pragma unroll
  for (int j = 0; j < 4; ++j) {
    unsigned u = (__float_as_uint(v[j]) + 0x8000u) & 0xFFFF0000u;
    hi[j] = (short)(u >> 16);
    float lf = v[j] - __uint_as_float(u);
    lo[j] = bf16h(lf);
  }
}

// One fold step: acc <- A * acc (3-term bf16 hi/lo split).
// av[R][H] = float4 A-frag: A[16R+col16][16H+4q .. +3].
__device__ __forceinline__ void fold_step(facc (&acc)[2][2], const float4 (&av)[2][2]) {
  bfrag Ahi[2][2], Alo[2][2], Bhi[2][2], Blo[2][2];
#pragma unroll
  for (int R = 0; R < 2; ++R)
#pragma unroll
    for (int H = 0; H < 2; ++H) {
      float v[4] = {av[R][H].x, av[R][H].y, av[R][H].z, av[R][H].w};
      split4(v, Ahi[R][H], Alo[R][H]);
    }
#pragma unroll
  for (int H = 0; H < 2; ++H)
#pragma unroll
    for (int c = 0; c < 2; ++c) {
      float v[4] = {acc[H][c][0], acc[H][c][1], acc[H][c][2], acc[H][c][3]};
      split4(v, Bhi[H][c], Blo[H][c]);
    }
  facc n[2][2];
#pragma unroll
  for (int R = 0; R < 2; ++R)
#pragma unroll
    for (int c = 0; c < 2; ++c) {
      facc z;
#pragma unroll
      for (int j = 0; j < 4; ++j) z[j] = 0.0f;
#pragma unroll
      for (int H = 0; H < 2; ++H) {
        z = MFMA16(Ahi[R][H], Bhi[H][c], z);
        z = MFMA16(Ahi[R][H], Blo[H][c], z);
        z = MFMA16(Alo[R][H], Bhi[H][c], z);
      }
      n[R][c] = z;
    }
#pragma unroll
  for (int R = 0; R < 2; ++R)
#pragma unroll
    for (int c = 0; c < 2; ++c) acc[R][c] = n[R][c];
}

// ---------------------------------------------------------------------------
// K0: core -> core2b. Coalesced reads, scattered 8B writes.
// src float4 v covers elements (i, c),(i, c+1): i=v>>4, c=2*(v&15).
// dest dword idx = ((r*2+h2)*64 + 16q+col16)*4 + j.
// ---------------------------------------------------------------------------
__global__ __launch_bounds__(256) void xform_k(const float* __restrict__ core,
                                               unsigned* __restrict__ core2b) {
  const int s = blockIdx.x;  // 0..783
  const int tid = threadIdx.x;
  const float4* src = (const float4*)(core + (size_t)s * 2048);
  unsigned* dst = core2b + (size_t)s * 1024;
#pragma unroll
  for (int u = 0; u < 2; ++u) {
    int v = tid + 256 * u;  // 0..511, coalesced
    float4 f = src[v];
    int i = v >> 4;
    int c = (v & 15) * 2;
    int r = i >> 4, col16 = i & 15;
    int h2 = c >> 4, cl = c & 15;
    int q = cl >> 2, j = cl & 3;  // j in {0,2}
    float e0a = f.x - ((i == c) ? 1.0f : 0.0f);
    float e0b = f.z - ((i == c + 1) ? 1.0f : 0.0f);
    unsigned wa = ((unsigned)(unsigned short)bf16h(f.y - f.x) << 16) |
                  (unsigned)(unsigned short)bf16h(e0a);
    unsigned wb = ((unsigned)(unsigned short)bf16h(f.w - f.z) << 16) |
                  (unsigned)(unsigned short)bf16h(e0b);
    int idx = ((r * 2 + h2) * 64 + 16 * q + col16) * 4 + j;
    *(uint2*)(dst + idx) = make_uint2(wa, wb);
  }
}

// ---------------------------------------------------------------------------
// K1 kchain: 512 blocks x 512 thr. bid -> chain = bid>>1, half = bid&1.
// Wave k (0..7) runs segment t = half*8 + k site loop, then 3-level LDS tree
// fold in T-world -> X_{chain,half} = T_{h8+7}...T_{h8} (T = S^T), row-major.
// ---------------------------------------------------------------------------
__global__ __launch_bounds__(512, 4) void kchain(const float* __restrict__ x,
                                                 const unsigned* __restrict__ core2b,
                                                 float* __restrict__ halfbuf) {
  const int tid = threadIdx.x;
  const int lane = tid & 63;
  const int k = tid >> 6;  // wave 0..7
  const int col16 = lane & 15;
  const int q = lane >> 4;

  const int bid = blockIdx.x;   // 0..511
  const int chain = bid >> 1;   // 0..255 = b*2 + hside
  const int half = bid & 1;
  const int b = chain >> 1;
  const int hside = chain & 1;

  const int t = half * 8 + k;  // global segment 0..15
  const int start = (t < 8) ? 25 * t : 200 + 24 * (t - 8);
  const int len = (t < 8) ? 25 : 24;
  const int s_lo = hside * 392 + start;
  const int s_hi = s_lo + len - 1;

  __shared__ float smX[8][32 * 36];  // padded row-major slots (stride 36)

  facc acc[2][2];
#pragma unroll
  for (int r = 0; r < 2; ++r)
#pragma unroll
    for (int c = 0; c < 2; ++c)
#pragma unroll
      for (int j = 0; j < 4; ++j)
        acc[r][c][j] = (16 * r + 4 * q + j == 16 * c + col16) ? 1.0f : 0.0f;

  const uint4* cp = (const uint4*)core2b;
  const float* xb = x + b * 784;

  // ---- segment site loop: acc = S_t (C/D layout) ----
  for (int s = s_hi; s >= s_lo; --s) {
    uint4 raw[4];  // frag f = r*2+h2
#pragma unroll
    for (int f = 0; f < 4; ++f) raw[f] = cp[(size_t)s * 256 + f * 64 + lane];
    const float xv = xb[s];

    // B = bf16(P_old) BEFORE accumulation (C/D layout == B layout, K=16)
    bfrag B[2][2];
#pragma unroll
    for (int h2 = 0; h2 < 2; ++h2)
#pragma unroll
      for (int c = 0; c < 2; ++c) B[h2][c] = pack4(acc[h2][c]);

    bfrag A[2][2];
#pragma unroll
    for (int r = 0; r < 2; ++r)
#pragma unroll
      for (int h2 = 0; h2 < 2; ++h2) {
        unsigned wd[4] = {raw[r * 2 + h2].x, raw[r * 2 + h2].y, raw[r * 2 + h2].z,
                          raw[r * 2 + h2].w};
        float e[4];
#pragma unroll
        for (int j = 0; j < 4; ++j) {
          float e0 = __uint_as_float(wd[j] << 16);
          float d = __uint_as_float(wd[j] & 0xFFFF0000u);
          e[j] = fmaf(xv, d, e0);
        }
        A[r][h2] = packf4(e[0], e[1], e[2], e[3]);
      }

#pragma unroll
    for (int r = 0; r < 2; ++r)
#pragma unroll
      for (int c = 0; c < 2; ++c) {
        acc[r][c] = MFMA16(A[r][0], B[0][c], acc[r][c]);
        acc[r][c] = MFMA16(A[r][1], B[1][c], acc[r][c]);
      }
  }

  // ---- publish T_k = S_t^T row-major (FIX: fragment-level transpose).
  // T[16c+col16][16r+4q+j] = S[16r+4q+j][16c+col16] = acc[r][c][j]; the j's
  // are contiguous -> float4 store, 16B-aligned (36 floats = 144B % 16 == 0).
#pragma unroll
  for (int r = 0; r < 2; ++r)
#pragma unroll
    for (int c = 0; c < 2; ++c)
      *(float4*)&smX[k][(16 * c + col16) * 36 + 16 * r + 4 * q] =
          make_float4(acc[r][c][0], acc[r][c][1], acc[r][c][2], acc[r][c][3]);
  __syncthreads();

  // consumer A-frag read of slot m gives A-frags of T_m (row-major source).
  facc a2[2][2];
#pragma unroll
  for (int r = 0; r < 2; ++r)
#pragma unroll
    for (int c = 0; c < 2; ++c)
#pragma unroll
      for (int j = 0; j < 4; ++j)
        a2[r][c][j] = (16 * r + 4 * q + j == 16 * c + col16) ? 1.0f : 0.0f;

  const int fo0 = (16 * 0 + col16) * 36 + 4 * q;
  const int fo1 = (16 * 1 + col16) * 36 + 4 * q;

  // L1: even waves fold pair (k, k+1): a2 = T_{k+1} * T_k
  if ((k & 1) == 0) {
    float4 av[2][2];
#pragma unroll
    for (int R = 0; R < 2; ++R)
#pragma unroll
      for (int H = 0; H < 2; ++H)
        av[R][H] = *(const float4*)&smX[k][(R ? fo1 : fo0) + 16 * H];
    fold_step(a2, av);  // = T_k
#pragma unroll
    for (int R = 0; R < 2; ++R)
#pragma unroll
      for (int H = 0; H < 2; ++H)
        av[R][H] = *(const float4*)&smX[k + 1][(R ? fo1 : fo0) + 16 * H];
    fold_step(a2, av);  // = T_{k+1} T_k
  }
  __syncthreads();
  // producers of L2: waves 2, 6 publish (a2 already T-world: row-major write)
  if (k == 2 || k == 6) {
#pragma unroll
    for (int r = 0; r < 2; ++r)
#pragma unroll
      for (int c = 0; c < 2; ++c)
#pragma unroll
        for (int j = 0; j < 4; ++j)
          smX[k][(16 * r + 4 * q + j) * 36 + 16 * c + col16] = a2[r][c][j];
  }
  __syncthreads();
  // L2: waves 0, 4 fold partner k+2
  if (k == 0 || k == 4) {
    float4 av[2][2];
#pragma unroll
    for (int R = 0; R < 2; ++R)
#pragma unroll
      for (int H = 0; H < 2; ++H)
        av[R][H] = *(const float4*)&smX[k + 2][(R ? fo1 : fo0) + 16 * H];
    fold_step(a2, av);  // = T_{k+3..k}
  }
  __syncthreads();
  // producer of L3: wave 4 publishes
  if (k == 4) {
#pragma unroll
    for (int r = 0; r < 2; ++r)
#pragma unroll
      for (int c = 0; c < 2; ++c)
#pragma unroll
        for (int j = 0; j < 4; ++j)
          smX[4][(16 * r + 4 * q + j) * 36 + 16 * c + col16] = a2[r][c][j];
  }
  __syncthreads();
  // L3: wave 0 folds slot 4 -> X = T_{half*8+7}...T_{half*8}; store row-major
  if (k == 0) {
    float4 av[2][2];
#pragma unroll
    for (int R = 0; R < 2; ++R)
#pragma unroll
      for (int H = 0; H < 2; ++H)
        av[R][H] = *(const float4*)&smX[4][(R ? fo1 : fo0) + 16 * H];
    fold_step(a2, av);
    float* rm = halfbuf + (size_t)bid * 1024;  // bid = chain*2 + half
#pragma unroll
    for (int r = 0; r < 2; ++r)
#pragma unroll
      for (int c = 0; c < 2; ++c)
#pragma unroll
        for (int j = 0; j < 4; ++j)
          rm[(16 * r + 4 * q + j) * 32 + 16 * c + col16] = a2[r][c][j];
  }
}

// ---------------------------------------------------------------------------
// K2 gfin: 128 blocks x 64 thr.
// H = Left^T * Right^T = X_L1 * X_L0 * X_R1 * X_R0 : 4 fold_steps from I,
// A-frags read from row-major half products. Then label contraction.
// ---------------------------------------------------------------------------
__global__ __launch_bounds__(64) void gfin(const float* __restrict__ halfbuf,
                                           const float* __restrict__ label,
                                           float* __restrict__ out) {
  const int lane = threadIdx.x;
  const int b = blockIdx.x;
  const int col16 = lane & 15;
  const int q = lane >> 4;

  __shared__ float smF[1024];

  facc acc[2][2];
#pragma unroll
  for (int r = 0; r < 2; ++r)
#pragma unroll
    for (int c = 0; c < 2; ++c)
#pragma unroll
      for (int j = 0; j < 4; ++j)
        acc[r][c][j] = (16 * r + 4 * q + j == 16 * c + col16) ? 1.0f : 0.0f;

  // fold order: X_R0, X_R1, X_L0, X_L1  (slot = chain*2 + half)
  const int slots[4] = {(2 * b + 1) * 2 + 0, (2 * b + 1) * 2 + 1,
                        (2 * b) * 2 + 0, (2 * b) * 2 + 1};
#pragma unroll
  for (int m = 0; m < 4; ++m) {
    const float* rm = halfbuf + (size_t)slots[m] * 1024;
    float4 av[2][2];
#pragma unroll
    for (int R = 0; R < 2; ++R)
#pragma unroll
      for (int H = 0; H < 2; ++H)
        av[R][H] = *(const float4*)&rm[(16 * R + col16) * 32 + 16 * H + 4 * q];
    fold_step(acc, av);
  }

  // acc = H = F^T (C/D layout); smF[j*32+k] = H[j][k]; label[(j*32+k)*10+l]
#pragma unroll
  for (int r = 0; r < 2; ++r)
#pragma unroll
    for (int c = 0; c < 2; ++c)
#pragma unroll
      for (int j = 0; j < 4; ++j)
        smF[(16 * r + 4 * q + j) * 32 + 16 * c + col16] = acc[r][c][j];
  __syncthreads();

  float part[10];
#pragma unroll
  for (int l = 0; l < 10; ++l) part[l] = 0.0f;
#pragma unroll
  for (int u = 0; u < 16; ++u) {
    int e = lane + 64 * u;
    float v = smF[e];
    const float* lb = label + (size_t)e * 10;
#pragma unroll
    for (int l = 0; l < 10; ++l) part[l] += v * lb[l];
  }
#pragma unroll
  for (int l = 0; l < 10; ++l) {
#pragma unroll
    for (int o = 32; o > 0; o >>= 1) part[l] += __shfl_xor(part[l], o, 64);
  }
  if (lane == 0) {
#pragma unroll
    for (int l = 0; l < 10; ++l) out[b * 10 + l] = part[l];
  }
}

extern "C" void kernel_launch(void* const* d_in, const int* in_sizes, int n_in,
                              void* d_out, int out_size, void* d_ws, size_t ws_size,
                              hipStream_t stream) {
  const float* x = (const float*)d_in[0];      // (128, 784)
  const float* core = (const float*)d_in[1];   // (784, 32, 32, 2)
  const float* label = (const float*)d_in[2];  // (32, 32, 10)
  float* out = (float*)d_out;                  // (128, 10)

  unsigned* core2b = (unsigned*)d_ws;                 // 3.2 MB
  float* halfbuf = (float*)d_ws + CORE2B_DWORDS;      // 2 MB

  hipLaunchKernelGGL(xform_k, dim3(784), dim3(256), 0, stream, core, core2b);
  hipLaunchKernelGGL(kchain, dim3(512), dim3(512), 0, stream, x, core2b, halfbuf);
  hipLaunchKernelGGL(gfin, dim3(128), dim3(64), 0, stream, halfbuf, label, out);
}